// Round 1
// baseline (2637.892 us; speedup 1.0000x reference)
//
#include <hip/hip_runtime.h>

#define NNODES 100000
#define NEDGES 1600000
#define NGRAPH 128
#define CIN 128
#define CH 64
#define COUT 7
#define NSTACK 9

// ---------------- degree count ----------------
__global__ void count_kernel(const int* __restrict__ dst, int* __restrict__ cnt, int E) {
    int e = blockIdx.x * blockDim.x + threadIdx.x;
    if (e < E) atomicAdd(&cnt[dst[e]], 1);
}

// ---------------- dinv + per-graph node counts ----------------
__global__ void dinv_kernel(const int* __restrict__ cnt, float* __restrict__ dinv,
                            const int* __restrict__ batch, int* __restrict__ gcnt, int N) {
    int i = blockIdx.x * blockDim.x + threadIdx.x;
    if (i < N) {
        // +1 for self-loop; always >= 1 so no zero-degree branch needed
        dinv[i] = 1.0f / sqrtf((float)(cnt[i] + 1));
        atomicAdd(&gcnt[batch[i]], 1);
    }
}

// ---------------- exclusive scan (3-phase) ----------------
__global__ void scan_a(const int* __restrict__ cnt, int* __restrict__ rowptr,
                       int* __restrict__ bsum, int N) {
    __shared__ int s[256];
    int i = blockIdx.x * 256 + threadIdx.x;
    int v = (i < N) ? cnt[i] : 0;
    s[threadIdx.x] = v;
    __syncthreads();
    for (int d = 1; d < 256; d <<= 1) {
        int t = (threadIdx.x >= d) ? s[threadIdx.x - d] : 0;
        __syncthreads();
        s[threadIdx.x] += t;
        __syncthreads();
    }
    if (i < N) rowptr[i] = s[threadIdx.x] - v;   // exclusive
    if (threadIdx.x == 255) bsum[blockIdx.x] = s[255];
}

__global__ void scan_b(int* __restrict__ bsum, int nb) {
    __shared__ int s[512];
    int v = (threadIdx.x < nb) ? bsum[threadIdx.x] : 0;
    s[threadIdx.x] = v;
    __syncthreads();
    for (int d = 1; d < 512; d <<= 1) {
        int t = (threadIdx.x >= (unsigned)d) ? s[threadIdx.x - d] : 0;
        __syncthreads();
        s[threadIdx.x] += t;
        __syncthreads();
    }
    if (threadIdx.x < nb) bsum[threadIdx.x] = s[threadIdx.x] - v;  // exclusive
}

__global__ void scan_c(int* __restrict__ rowptr, const int* __restrict__ bsum, int N) {
    int i = blockIdx.x * 256 + threadIdx.x;
    if (i < N) rowptr[i] += bsum[blockIdx.x];
}

// ---------------- CSR fill ----------------
__global__ void fill_kernel(const int* __restrict__ src, const int* __restrict__ dst,
                            const int* __restrict__ rowptr, int* __restrict__ fill,
                            int* __restrict__ col, int E) {
    int e = blockIdx.x * blockDim.x + threadIdx.x;
    if (e < E) {
        int d = dst[e];
        int p = atomicAdd(&fill[d], 1);
        col[rowptr[d] + p] = src[e];
    }
}

// ---------------- GEMM m = h @ W  (wave per row, lane per out-channel) ----------------
template <int K>
__global__ __launch_bounds__(256) void gemm_kernel(const float* __restrict__ h,
                                                   const float* __restrict__ W,
                                                   float* __restrict__ m, int N) {
    __shared__ float Ws[K * 64];
    for (int i = threadIdx.x; i < K * 64; i += 256) Ws[i] = W[i];
    __syncthreads();
    int wid = (blockIdx.x * 256 + threadIdx.x) >> 6;
    int lane = threadIdx.x & 63;
    if (wid >= N) return;
    const float* hr = h + (size_t)wid * K;
    float acc = 0.0f;
    float h0 = hr[lane];
    if (K == 64) {
#pragma unroll
        for (int k = 0; k < 64; ++k) acc += __shfl(h0, k) * Ws[k * 64 + lane];
    } else {
        float h1 = hr[64 + lane];
#pragma unroll
        for (int k = 0; k < 64; ++k) acc += __shfl(h0, k) * Ws[k * 64 + lane];
#pragma unroll
        for (int k = 0; k < 64; ++k) acc += __shfl(h1, k) * Ws[(64 + k) * 64 + lane];
    }
    m[wid * 64 + lane] = acc;
}

// ---------------- aggregation: h' = relu(dinv_i*(sum_src dinv_src*m[src] + dinv_i*m[i]) + b) ----
__global__ __launch_bounds__(256) void agg_kernel(const float* __restrict__ m,
                                                  const int* __restrict__ rowptr,
                                                  const int* __restrict__ col,
                                                  const float* __restrict__ dinv,
                                                  const float* __restrict__ bias,
                                                  float* __restrict__ hout, int N, int E) {
    int wid = (blockIdx.x * 256 + threadIdx.x) >> 6;
    int lane = threadIdx.x & 63;
    if (wid >= N) return;
    int r0 = rowptr[wid];
    int r1 = (wid + 1 < N) ? rowptr[wid + 1] : E;
    float di = dinv[wid];
    float s = di * m[wid * 64 + lane];   // self-loop term (before outer di multiply)
    for (int base = r0; base < r1; base += 64) {
        int nn = min(64, r1 - base);
        int sv = (lane < nn) ? col[base + lane] : 0;
        float dv = (lane < nn) ? dinv[sv] : 0.0f;
        for (int k = 0; k < nn; ++k) {
            int srci = __shfl(sv, k);
            float ds = __shfl(dv, k);
            s += ds * m[srci * 64 + lane];
        }
    }
    float v = di * s + bias[lane];
    hout[wid * 64 + lane] = fmaxf(v, 0.0f);
}

// ---------------- pooling: segment sum over sorted batch ids ----------------
__global__ __launch_bounds__(256) void pool_kernel(const float* __restrict__ h,
                                                   const int* __restrict__ batch,
                                                   float* __restrict__ gpool, int N) {
    const int NPW = 32;  // nodes per wave
    int wid = (blockIdx.x * 256 + threadIdx.x) >> 6;
    int lane = threadIdx.x & 63;
    int i0 = wid * NPW;
    if (i0 >= N) return;
    int i1 = min(i0 + NPW, N);
    int curg = batch[i0];
    float acc = 0.0f;
    for (int i = i0; i < i1; ++i) {
        int g = batch[i];
        if (g != curg) {
            atomicAdd(&gpool[curg * 64 + lane], acc);
            acc = 0.0f;
            curg = g;
        }
        acc += h[i * 64 + lane];
    }
    atomicAdd(&gpool[curg * 64 + lane], acc);
}

// ---------------- final: out = (gpool/count) @ Wlin + blin ----------------
__global__ void final_kernel(const float* __restrict__ gpool, const int* __restrict__ gcnt,
                             const float* __restrict__ Wlin, const float* __restrict__ blin,
                             float* __restrict__ out) {
    int t = threadIdx.x;
    if (t >= NGRAPH * COUT) return;
    int g = t / COUT, o = t - g * COUT;
    float c = (float)gcnt[g];
    if (c < 1.0f) c = 1.0f;
    float s = 0.0f;
    for (int k = 0; k < 64; ++k) s += gpool[g * 64 + k] * Wlin[k * COUT + o];
    out[t] = s / c + blin[o];
}

extern "C" void kernel_launch(void* const* d_in, const int* in_sizes, int n_in,
                              void* d_out, int out_size, void* d_ws, size_t ws_size,
                              hipStream_t stream) {
    const float* x    = (const float*)d_in[0];
    const int*   ei   = (const int*)d_in[1];
    const int*   batch= (const int*)d_in[2];
    const float* W0   = (const float*)d_in[3];
    const float* b0   = (const float*)d_in[4];
    const float* Ws   = (const float*)d_in[5];
    const float* bs   = (const float*)d_in[6];
    const float* Wlin = (const float*)d_in[7];
    const float* blin = (const float*)d_in[8];
    float* out = (float*)d_out;

    const int N = NNODES, E = NEDGES;
    const int* srcp = ei;          // edge_index[0]
    const int* dstp = ei + E;      // edge_index[1]

    char* w = (char*)d_ws;
    int*   cnt    = (int*)w;   w += (size_t)N * 4;
    int*   fill   = (int*)w;   w += (size_t)N * 4;
    float* gpool  = (float*)w; w += (size_t)NGRAPH * 64 * 4;
    int*   gcnt   = (int*)w;   w += (size_t)NGRAPH * 4;
    int*   bsum   = (int*)w;   w += (size_t)512 * 4;
    size_t zero_bytes = (size_t)(w - (char*)d_ws);
    float* dinv   = (float*)w; w += (size_t)N * 4;
    int*   rowptr = (int*)w;   w += (size_t)N * 4;
    int*   col    = (int*)w;   w += (size_t)E * 4;
    float* bufA   = (float*)w; w += (size_t)N * 64 * 4;
    float* bufB   = (float*)w; w += (size_t)N * 64 * 4;

    hipMemsetAsync(d_ws, 0, zero_bytes, stream);

    int eblocks = (E + 255) / 256;
    int nblocks = (N + 255) / 256;   // 391, fits scan_b's 512-thread block

    count_kernel<<<eblocks, 256, 0, stream>>>(dstp, cnt, E);
    dinv_kernel<<<nblocks, 256, 0, stream>>>(cnt, dinv, batch, gcnt, N);
    scan_a<<<nblocks, 256, 0, stream>>>(cnt, rowptr, bsum, N);
    scan_b<<<1, 512, 0, stream>>>(bsum, nblocks);
    scan_c<<<nblocks, 256, 0, stream>>>(rowptr, bsum, N);
    fill_kernel<<<eblocks, 256, 0, stream>>>(srcp, dstp, rowptr, fill, col, E);

    int gwblocks = (N + 3) / 4;  // wave (64 lanes) per node, 4 waves/block

    // layer 0: [N,128] @ [128,64]
    gemm_kernel<128><<<gwblocks, 256, 0, stream>>>(x, W0, bufB, N);
    agg_kernel<<<gwblocks, 256, 0, stream>>>(bufB, rowptr, col, dinv, b0, bufA, N, E);

    // 9 stacked layers: [N,64] @ [64,64]
    for (int l = 0; l < NSTACK; ++l) {
        gemm_kernel<64><<<gwblocks, 256, 0, stream>>>(bufA, Ws + (size_t)l * 64 * 64, bufB, N);
        agg_kernel<<<gwblocks, 256, 0, stream>>>(bufB, rowptr, col, dinv, bs + (size_t)l * 64,
                                                 bufA, N, E);
    }

    int pwaves = (N + 31) / 32;
    int pblocks = (pwaves + 3) / 4;
    pool_kernel<<<pblocks, 256, 0, stream>>>(bufA, batch, gpool, N);
    final_kernel<<<1, 896, 0, stream>>>(gpool, gcnt, Wlin, blin, out);
}

// Round 2
// 2358.600 us; speedup vs baseline: 1.1184x; 1.1184x over previous
//
#include <hip/hip_runtime.h>

#define NNODES 100000
#define NEDGES 1600000
#define NGRAPH 128
#define CIN 128
#define CH 64
#define COUT 7
#define NSTACK 9

// ---------------- degree count ----------------
__global__ void count_kernel(const int* __restrict__ dst, int* __restrict__ cnt, int E) {
    int e = blockIdx.x * blockDim.x + threadIdx.x;
    if (e < E) atomicAdd(&cnt[dst[e]], 1);
}

// ---------------- dinv (streaming only, no atomics) ----------------
__global__ void dinv_kernel(const int* __restrict__ cnt, float* __restrict__ dinv, int N) {
    int i = blockIdx.x * blockDim.x + threadIdx.x;
    if (i < N) {
        // +1 for self-loop; always >= 1 so no zero-degree branch needed
        dinv[i] = 1.0f / sqrtf((float)(cnt[i] + 1));
    }
}

// ---------------- per-graph node counts via binary search (batch is sorted) ----------------
__global__ void gcnt_kernel(const int* __restrict__ batch, int* __restrict__ gcnt, int N) {
    int g = threadIdx.x;
    if (g >= NGRAPH) return;
    // lower_bound(batch, v)
    auto lb = [&](int v) {
        int lo = 0, hi = N;
        while (lo < hi) {
            int mid = (lo + hi) >> 1;
            if (batch[mid] < v) lo = mid + 1; else hi = mid;
        }
        return lo;
    };
    gcnt[g] = lb(g + 1) - lb(g);
}

// ---------------- exclusive scan (3-phase) ----------------
__global__ void scan_a(const int* __restrict__ cnt, int* __restrict__ rowptr,
                       int* __restrict__ bsum, int N) {
    __shared__ int s[256];
    int i = blockIdx.x * 256 + threadIdx.x;
    int v = (i < N) ? cnt[i] : 0;
    s[threadIdx.x] = v;
    __syncthreads();
    for (int d = 1; d < 256; d <<= 1) {
        int t = (threadIdx.x >= d) ? s[threadIdx.x - d] : 0;
        __syncthreads();
        s[threadIdx.x] += t;
        __syncthreads();
    }
    if (i < N) rowptr[i] = s[threadIdx.x] - v;   // exclusive
    if (threadIdx.x == 255) bsum[blockIdx.x] = s[255];
}

__global__ void scan_b(int* __restrict__ bsum, int nb) {
    __shared__ int s[512];
    int v = (threadIdx.x < nb) ? bsum[threadIdx.x] : 0;
    s[threadIdx.x] = v;
    __syncthreads();
    for (int d = 1; d < 512; d <<= 1) {
        int t = (threadIdx.x >= (unsigned)d) ? s[threadIdx.x - d] : 0;
        __syncthreads();
        s[threadIdx.x] += t;
        __syncthreads();
    }
    if (threadIdx.x < nb) bsum[threadIdx.x] = s[threadIdx.x] - v;  // exclusive
}

__global__ void scan_c(int* __restrict__ rowptr, const int* __restrict__ bsum, int N) {
    int i = blockIdx.x * 256 + threadIdx.x;
    if (i < N) rowptr[i] += bsum[blockIdx.x];
}

// ---------------- CSR fill ----------------
__global__ void fill_kernel(const int* __restrict__ src, const int* __restrict__ dst,
                            const int* __restrict__ rowptr, int* __restrict__ fill,
                            int* __restrict__ col, int E) {
    int e = blockIdx.x * blockDim.x + threadIdx.x;
    if (e < E) {
        int d = dst[e];
        int p = atomicAdd(&fill[d], 1);
        col[rowptr[d] + p] = src[e];
    }
}

// ---------------- GEMM m = h @ W  (wave per row, lane per out-channel) ----------------
template <int K>
__global__ __launch_bounds__(256) void gemm_kernel(const float* __restrict__ h,
                                                   const float* __restrict__ W,
                                                   float* __restrict__ m, int N) {
    __shared__ float Ws[K * 64];
    for (int i = threadIdx.x; i < K * 64; i += 256) Ws[i] = W[i];
    __syncthreads();
    int wid = (blockIdx.x * 256 + threadIdx.x) >> 6;
    int lane = threadIdx.x & 63;
    if (wid >= N) return;
    const float* hr = h + (size_t)wid * K;
    float acc = 0.0f;
    float h0 = hr[lane];
    if (K == 64) {
#pragma unroll
        for (int k = 0; k < 64; ++k) acc += __shfl(h0, k) * Ws[k * 64 + lane];
    } else {
        float h1 = hr[64 + lane];
#pragma unroll
        for (int k = 0; k < 64; ++k) acc += __shfl(h0, k) * Ws[k * 64 + lane];
#pragma unroll
        for (int k = 0; k < 64; ++k) acc += __shfl(h1, k) * Ws[(64 + k) * 64 + lane];
    }
    m[wid * 64 + lane] = acc;
}

// ---------------- aggregation: h' = relu(dinv_i*(sum_src dinv_src*m[src] + dinv_i*m[i]) + b) ----
__global__ __launch_bounds__(256) void agg_kernel(const float* __restrict__ m,
                                                  const int* __restrict__ rowptr,
                                                  const int* __restrict__ col,
                                                  const float* __restrict__ dinv,
                                                  const float* __restrict__ bias,
                                                  float* __restrict__ hout, int N, int E) {
    int wid = (blockIdx.x * 256 + threadIdx.x) >> 6;
    int lane = threadIdx.x & 63;
    if (wid >= N) return;
    int r0 = rowptr[wid];
    int r1 = (wid + 1 < N) ? rowptr[wid + 1] : E;
    float di = dinv[wid];
    float s = di * m[wid * 64 + lane];   // self-loop term (before outer di multiply)
    for (int base = r0; base < r1; base += 64) {
        int nn = min(64, r1 - base);
        int sv = (lane < nn) ? col[base + lane] : 0;
        float dv = (lane < nn) ? dinv[sv] : 0.0f;
        for (int k = 0; k < nn; ++k) {
            int srci = __shfl(sv, k);
            float ds = __shfl(dv, k);
            s += ds * m[srci * 64 + lane];
        }
    }
    float v = di * s + bias[lane];
    hout[wid * 64 + lane] = fmaxf(v, 0.0f);
}

// ---------------- pooling: segment sum over sorted batch ids ----------------
__global__ __launch_bounds__(256) void pool_kernel(const float* __restrict__ h,
                                                   const int* __restrict__ batch,
                                                   float* __restrict__ gpool, int N) {
    const int NPW = 32;  // nodes per wave
    int wid = (blockIdx.x * 256 + threadIdx.x) >> 6;
    int lane = threadIdx.x & 63;
    int i0 = wid * NPW;
    if (i0 >= N) return;
    int i1 = min(i0 + NPW, N);
    int curg = batch[i0];
    float acc = 0.0f;
    for (int i = i0; i < i1; ++i) {
        int g = batch[i];
        if (g != curg) {
            atomicAdd(&gpool[curg * 64 + lane], acc);
            acc = 0.0f;
            curg = g;
        }
        acc += h[i * 64 + lane];
    }
    atomicAdd(&gpool[curg * 64 + lane], acc);
}

// ---------------- final: out = (gpool/count) @ Wlin + blin ----------------
__global__ void final_kernel(const float* __restrict__ gpool, const int* __restrict__ gcnt,
                             const float* __restrict__ Wlin, const float* __restrict__ blin,
                             float* __restrict__ out) {
    int t = threadIdx.x;
    if (t >= NGRAPH * COUT) return;
    int g = t / COUT, o = t - g * COUT;
    float c = (float)gcnt[g];
    if (c < 1.0f) c = 1.0f;
    float s = 0.0f;
    for (int k = 0; k < 64; ++k) s += gpool[g * 64 + k] * Wlin[k * COUT + o];
    out[t] = s / c + blin[o];
}

extern "C" void kernel_launch(void* const* d_in, const int* in_sizes, int n_in,
                              void* d_out, int out_size, void* d_ws, size_t ws_size,
                              hipStream_t stream) {
    const float* x    = (const float*)d_in[0];
    const int*   ei   = (const int*)d_in[1];
    const int*   batch= (const int*)d_in[2];
    const float* W0   = (const float*)d_in[3];
    const float* b0   = (const float*)d_in[4];
    const float* Ws   = (const float*)d_in[5];
    const float* bs   = (const float*)d_in[6];
    const float* Wlin = (const float*)d_in[7];
    const float* blin = (const float*)d_in[8];
    float* out = (float*)d_out;

    const int N = NNODES, E = NEDGES;
    const int* srcp = ei;          // edge_index[0]
    const int* dstp = ei + E;      // edge_index[1]

    char* w = (char*)d_ws;
    int*   cnt    = (int*)w;   w += (size_t)N * 4;
    int*   fill   = (int*)w;   w += (size_t)N * 4;
    float* gpool  = (float*)w; w += (size_t)NGRAPH * 64 * 4;
    size_t zero_bytes = (size_t)(w - (char*)d_ws);
    int*   gcnt   = (int*)w;   w += (size_t)NGRAPH * 4;
    int*   bsum   = (int*)w;   w += (size_t)512 * 4;
    float* dinv   = (float*)w; w += (size_t)N * 4;
    int*   rowptr = (int*)w;   w += (size_t)N * 4;
    int*   col    = (int*)w;   w += (size_t)E * 4;
    float* bufA   = (float*)w; w += (size_t)N * 64 * 4;
    float* bufB   = (float*)w; w += (size_t)N * 64 * 4;

    hipMemsetAsync(d_ws, 0, zero_bytes, stream);

    int eblocks = (E + 255) / 256;
    int nblocks = (N + 255) / 256;   // 391, fits scan_b's 512-thread block

    count_kernel<<<eblocks, 256, 0, stream>>>(dstp, cnt, E);
    dinv_kernel<<<nblocks, 256, 0, stream>>>(cnt, dinv, N);
    gcnt_kernel<<<1, 128, 0, stream>>>(batch, gcnt, N);
    scan_a<<<nblocks, 256, 0, stream>>>(cnt, rowptr, bsum, N);
    scan_b<<<1, 512, 0, stream>>>(bsum, nblocks);
    scan_c<<<nblocks, 256, 0, stream>>>(rowptr, bsum, N);
    fill_kernel<<<eblocks, 256, 0, stream>>>(srcp, dstp, rowptr, fill, col, E);

    int gwblocks = (N + 3) / 4;  // wave (64 lanes) per node, 4 waves/block

    // layer 0: [N,128] @ [128,64]
    gemm_kernel<128><<<gwblocks, 256, 0, stream>>>(x, W0, bufB, N);
    agg_kernel<<<gwblocks, 256, 0, stream>>>(bufB, rowptr, col, dinv, b0, bufA, N, E);

    // 9 stacked layers: [N,64] @ [64,64]
    for (int l = 0; l < NSTACK; ++l) {
        gemm_kernel<64><<<gwblocks, 256, 0, stream>>>(bufA, Ws + (size_t)l * 64 * 64, bufB, N);
        agg_kernel<<<gwblocks, 256, 0, stream>>>(bufB, rowptr, col, dinv, bs + (size_t)l * 64,
                                                 bufA, N, E);
    }

    int pwaves = (N + 31) / 32;
    int pblocks = (pwaves + 3) / 4;
    pool_kernel<<<pblocks, 256, 0, stream>>>(bufA, batch, gpool, N);
    final_kernel<<<1, 896, 0, stream>>>(gpool, gcnt, Wlin, blin, out);
}

// Round 3
// 1544.557 us; speedup vs baseline: 1.7079x; 1.5270x over previous
//
#include <hip/hip_runtime.h>

#define NNODES 100000
#define NEDGES 1600000
#define NGRAPH 128
#define CIN 128
#define CH 64
#define COUT 7
#define NSTACK 9

// ---------------- degree count ----------------
__global__ void count_kernel(const int* __restrict__ dst, int* __restrict__ cnt, int E) {
    int e = blockIdx.x * blockDim.x + threadIdx.x;
    if (e < E) atomicAdd(&cnt[dst[e]], 1);
}

// ---------------- dinv (streaming only, no atomics) ----------------
__global__ void dinv_kernel(const int* __restrict__ cnt, float* __restrict__ dinv, int N) {
    int i = blockIdx.x * blockDim.x + threadIdx.x;
    if (i < N) {
        dinv[i] = 1.0f / sqrtf((float)(cnt[i] + 1));  // +1 self-loop, always >= 1
    }
}

// ---------------- per-graph node counts via binary search (batch is sorted) ----------------
__global__ void gcnt_kernel(const int* __restrict__ batch, int* __restrict__ gcnt, int N) {
    int g = threadIdx.x;
    if (g >= NGRAPH) return;
    auto lb = [&](int v) {
        int lo = 0, hi = N;
        while (lo < hi) {
            int mid = (lo + hi) >> 1;
            if (batch[mid] < v) lo = mid + 1; else hi = mid;
        }
        return lo;
    };
    gcnt[g] = lb(g + 1) - lb(g);
}

// ---------------- exclusive scan (3-phase) ----------------
__global__ void scan_a(const int* __restrict__ cnt, int* __restrict__ rowptr,
                       int* __restrict__ bsum, int N) {
    __shared__ int s[256];
    int i = blockIdx.x * 256 + threadIdx.x;
    int v = (i < N) ? cnt[i] : 0;
    s[threadIdx.x] = v;
    __syncthreads();
    for (int d = 1; d < 256; d <<= 1) {
        int t = (threadIdx.x >= d) ? s[threadIdx.x - d] : 0;
        __syncthreads();
        s[threadIdx.x] += t;
        __syncthreads();
    }
    if (i < N) rowptr[i] = s[threadIdx.x] - v;   // exclusive
    if (threadIdx.x == 255) bsum[blockIdx.x] = s[255];
}

__global__ void scan_b(int* __restrict__ bsum, int nb) {
    __shared__ int s[512];
    int v = (threadIdx.x < nb) ? bsum[threadIdx.x] : 0;
    s[threadIdx.x] = v;
    __syncthreads();
    for (int d = 1; d < 512; d <<= 1) {
        int t = (threadIdx.x >= (unsigned)d) ? s[threadIdx.x - d] : 0;
        __syncthreads();
        s[threadIdx.x] += t;
        __syncthreads();
    }
    if (threadIdx.x < nb) bsum[threadIdx.x] = s[threadIdx.x] - v;  // exclusive
}

__global__ void scan_c(int* __restrict__ rowptr, const int* __restrict__ bsum, int N) {
    int i = blockIdx.x * 256 + threadIdx.x;
    if (i < N) rowptr[i] += bsum[blockIdx.x];
}

// ---------------- CSR fill (also precompute per-edge dinv[src]) ----------------
__global__ void fill_kernel(const int* __restrict__ src, const int* __restrict__ dst,
                            const int* __restrict__ rowptr, int* __restrict__ fill,
                            int* __restrict__ col, float* __restrict__ dn,
                            const float* __restrict__ dinv, int E) {
    int e = blockIdx.x * blockDim.x + threadIdx.x;
    if (e < E) {
        int d = dst[e];
        int s = src[e];
        int p = atomicAdd(&fill[d], 1);
        int idx = rowptr[d] + p;
        col[idx] = s;
        dn[idx] = dinv[s];
    }
}

// ---------------- GEMM m = h @ W ----------------
// 8 rows per wave, lane = output column. W[k][lane] from LDS (1 read per k,
// 2-way bank aliasing = free), h broadcast via v_readlane (no LDS), 8
// independent accumulator chains for ILP.
template <int K>
__global__ __launch_bounds__(256) void gemm_kernel(const float* __restrict__ h,
                                                   const float* __restrict__ W,
                                                   float* __restrict__ m, int N) {
    __shared__ float Ws[K * 64];
    for (int i = threadIdx.x; i < K * 64; i += 256) Ws[i] = W[i];
    __syncthreads();
    const int ROWS = 8;
    int wid = (blockIdx.x * 256 + threadIdx.x) >> 6;
    int lane = threadIdx.x & 63;
    long row0 = (long)wid * ROWS;
    if (row0 >= N) return;
    const float* hr = h + row0 * K + lane;

    float hv[ROWS][K / 64];
#pragma unroll
    for (int r = 0; r < ROWS; ++r)
#pragma unroll
        for (int q = 0; q < K / 64; ++q)
            hv[r][q] = hr[(size_t)r * K + q * 64];

    float acc[ROWS];
#pragma unroll
    for (int r = 0; r < ROWS; ++r) acc[r] = 0.0f;

#pragma unroll
    for (int k = 0; k < K; ++k) {
        float wv = Ws[k * 64 + lane];
#pragma unroll
        for (int r = 0; r < ROWS; ++r) {
            unsigned hb = __builtin_amdgcn_readlane(__float_as_uint(hv[r][k >> 6]), k & 63);
            acc[r] += __uint_as_float(hb) * wv;
        }
    }

    float* mo = m + row0 * 64 + lane;
#pragma unroll
    for (int r = 0; r < ROWS; ++r) mo[r * 64] = acc[r];
}

// ---------------- aggregation: h' = relu(dinv_i*(sum_src dn_e*m[src] + dinv_i*m[i]) + b) ----
__global__ __launch_bounds__(256) void agg_kernel(const float* __restrict__ m,
                                                  const int* __restrict__ rowptr,
                                                  const int* __restrict__ col,
                                                  const float* __restrict__ dn,
                                                  const float* __restrict__ dinv,
                                                  const float* __restrict__ bias,
                                                  float* __restrict__ hout, int N, int E) {
    int wid = (blockIdx.x * 256 + threadIdx.x) >> 6;
    int lane = threadIdx.x & 63;
    if (wid >= N) return;
    int r0 = rowptr[wid];
    int r1 = (wid + 1 < N) ? rowptr[wid + 1] : E;
    float di = dinv[wid];
    float s = di * m[wid * 64 + lane];   // self-loop term (before outer di multiply)
    for (int base = r0; base < r1; base += 64) {
        int nn = min(64, r1 - base);
        int sv = (lane < nn) ? col[base + lane] : 0;
        float dv = (lane < nn) ? dn[base + lane] : 0.0f;
        for (int k = 0; k < nn; ++k) {
            int srci = __shfl(sv, k);
            float ds = __shfl(dv, k);
            s += ds * m[srci * 64 + lane];
        }
    }
    float v = di * s + bias[lane];
    hout[wid * 64 + lane] = fmaxf(v, 0.0f);
}

// ---------------- pooling: segment sum over sorted batch ids ----------------
__global__ __launch_bounds__(256) void pool_kernel(const float* __restrict__ h,
                                                   const int* __restrict__ batch,
                                                   float* __restrict__ gpool, int N) {
    const int NPW = 32;  // nodes per wave
    int wid = (blockIdx.x * 256 + threadIdx.x) >> 6;
    int lane = threadIdx.x & 63;
    int i0 = wid * NPW;
    if (i0 >= N) return;
    int i1 = min(i0 + NPW, N);
    int curg = batch[i0];
    float acc = 0.0f;
    for (int i = i0; i < i1; ++i) {
        int g = batch[i];
        if (g != curg) {
            atomicAdd(&gpool[curg * 64 + lane], acc);
            acc = 0.0f;
            curg = g;
        }
        acc += h[i * 64 + lane];
    }
    atomicAdd(&gpool[curg * 64 + lane], acc);
}

// ---------------- final: out = (gpool/count) @ Wlin + blin ----------------
__global__ void final_kernel(const float* __restrict__ gpool, const int* __restrict__ gcnt,
                             const float* __restrict__ Wlin, const float* __restrict__ blin,
                             float* __restrict__ out) {
    int t = threadIdx.x;
    if (t >= NGRAPH * COUT) return;
    int g = t / COUT, o = t - g * COUT;
    float c = (float)gcnt[g];
    if (c < 1.0f) c = 1.0f;
    float s = 0.0f;
    for (int k = 0; k < 64; ++k) s += gpool[g * 64 + k] * Wlin[k * COUT + o];
    out[t] = s / c + blin[o];
}

extern "C" void kernel_launch(void* const* d_in, const int* in_sizes, int n_in,
                              void* d_out, int out_size, void* d_ws, size_t ws_size,
                              hipStream_t stream) {
    const float* x    = (const float*)d_in[0];
    const int*   ei   = (const int*)d_in[1];
    const int*   batch= (const int*)d_in[2];
    const float* W0   = (const float*)d_in[3];
    const float* b0   = (const float*)d_in[4];
    const float* Ws   = (const float*)d_in[5];
    const float* bs   = (const float*)d_in[6];
    const float* Wlin = (const float*)d_in[7];
    const float* blin = (const float*)d_in[8];
    float* out = (float*)d_out;

    const int N = NNODES, E = NEDGES;
    const int* srcp = ei;          // edge_index[0]
    const int* dstp = ei + E;      // edge_index[1]

    char* w = (char*)d_ws;
    int*   cnt    = (int*)w;   w += (size_t)N * 4;
    int*   fill   = (int*)w;   w += (size_t)N * 4;
    float* gpool  = (float*)w; w += (size_t)NGRAPH * 64 * 4;
    size_t zero_bytes = (size_t)(w - (char*)d_ws);
    int*   gcnt   = (int*)w;   w += (size_t)NGRAPH * 4;
    int*   bsum   = (int*)w;   w += (size_t)512 * 4;
    float* dinv   = (float*)w; w += (size_t)N * 4;
    int*   rowptr = (int*)w;   w += (size_t)N * 4;
    int*   col    = (int*)w;   w += (size_t)E * 4;
    float* dn     = (float*)w; w += (size_t)E * 4;
    float* bufA   = (float*)w; w += (size_t)N * 64 * 4;
    float* bufB   = (float*)w; w += (size_t)N * 64 * 4;

    hipMemsetAsync(d_ws, 0, zero_bytes, stream);

    int eblocks = (E + 255) / 256;
    int nblocks = (N + 255) / 256;   // 391, fits scan_b's 512-thread block

    count_kernel<<<eblocks, 256, 0, stream>>>(dstp, cnt, E);
    dinv_kernel<<<nblocks, 256, 0, stream>>>(cnt, dinv, N);
    gcnt_kernel<<<1, 128, 0, stream>>>(batch, gcnt, N);
    scan_a<<<nblocks, 256, 0, stream>>>(cnt, rowptr, bsum, N);
    scan_b<<<1, 512, 0, stream>>>(bsum, nblocks);
    scan_c<<<nblocks, 256, 0, stream>>>(rowptr, bsum, N);
    fill_kernel<<<eblocks, 256, 0, stream>>>(srcp, dstp, rowptr, fill, col, dn, dinv, E);

    // GEMM: 8 rows/wave, 4 waves/block -> 32 rows/block
    int gemmblocks = (N + 31) / 32;
    int aggblocks = (N + 3) / 4;     // wave per node, 4 waves/block

    // layer 0: [N,128] @ [128,64]
    gemm_kernel<128><<<gemmblocks, 256, 0, stream>>>(x, W0, bufB, N);
    agg_kernel<<<aggblocks, 256, 0, stream>>>(bufB, rowptr, col, dn, dinv, b0, bufA, N, E);

    // 9 stacked layers: [N,64] @ [64,64]
    for (int l = 0; l < NSTACK; ++l) {
        gemm_kernel<64><<<gemmblocks, 256, 0, stream>>>(bufA, Ws + (size_t)l * 64 * 64, bufB, N);
        agg_kernel<<<aggblocks, 256, 0, stream>>>(bufB, rowptr, col, dn, dinv, bs + (size_t)l * 64,
                                                  bufA, N, E);
    }

    int pwaves = (N + 31) / 32;
    int pblocks = (pwaves + 3) / 4;
    pool_kernel<<<pblocks, 256, 0, stream>>>(bufA, batch, gpool, N);
    final_kernel<<<1, 896, 0, stream>>>(gpool, gcnt, Wlin, blin, out);
}

// Round 4
// 1110.985 us; speedup vs baseline: 2.3744x; 1.3903x over previous
//
#include <hip/hip_runtime.h>

#define NNODES 100000
#define NEDGES 1600000
#define NGRAPH 128
#define CIN 128
#define CH 64
#define COUT 7
#define NSTACK 9

struct alignas(8) Edge { int c; float d; };

// ---------------- degree count ----------------
__global__ void count_kernel(const int* __restrict__ dst, int* __restrict__ cnt, int E) {
    int e = blockIdx.x * blockDim.x + threadIdx.x;
    if (e < E) atomicAdd(&cnt[dst[e]], 1);
}

// ---------------- dinv (streaming only, no atomics) ----------------
__global__ void dinv_kernel(const int* __restrict__ cnt, float* __restrict__ dinv, int N) {
    int i = blockIdx.x * blockDim.x + threadIdx.x;
    if (i < N) {
        dinv[i] = 1.0f / sqrtf((float)(cnt[i] + 1));  // +1 self-loop, always >= 1
    }
}

// ---------------- per-graph node counts via binary search (batch is sorted) ----------------
__global__ void gcnt_kernel(const int* __restrict__ batch, int* __restrict__ gcnt, int N) {
    int g = threadIdx.x;
    if (g >= NGRAPH) return;
    auto lb = [&](int v) {
        int lo = 0, hi = N;
        while (lo < hi) {
            int mid = (lo + hi) >> 1;
            if (batch[mid] < v) lo = mid + 1; else hi = mid;
        }
        return lo;
    };
    gcnt[g] = lb(g + 1) - lb(g);
}

// ---------------- exclusive scan (3-phase) ----------------
__global__ void scan_a(const int* __restrict__ cnt, int* __restrict__ rowptr,
                       int* __restrict__ bsum, int N) {
    __shared__ int s[256];
    int i = blockIdx.x * 256 + threadIdx.x;
    int v = (i < N) ? cnt[i] : 0;
    s[threadIdx.x] = v;
    __syncthreads();
    for (int d = 1; d < 256; d <<= 1) {
        int t = (threadIdx.x >= d) ? s[threadIdx.x - d] : 0;
        __syncthreads();
        s[threadIdx.x] += t;
        __syncthreads();
    }
    if (i < N) rowptr[i] = s[threadIdx.x] - v;   // exclusive
    if (threadIdx.x == 255) bsum[blockIdx.x] = s[255];
}

__global__ void scan_b(int* __restrict__ bsum, int nb) {
    __shared__ int s[512];
    int v = (threadIdx.x < nb) ? bsum[threadIdx.x] : 0;
    s[threadIdx.x] = v;
    __syncthreads();
    for (int d = 1; d < 512; d <<= 1) {
        int t = (threadIdx.x >= (unsigned)d) ? s[threadIdx.x - d] : 0;
        __syncthreads();
        s[threadIdx.x] += t;
        __syncthreads();
    }
    if (threadIdx.x < nb) bsum[threadIdx.x] = s[threadIdx.x] - v;  // exclusive
}

__global__ void scan_c(int* __restrict__ rowptr, const int* __restrict__ bsum, int N) {
    int i = blockIdx.x * 256 + threadIdx.x;
    if (i < N) rowptr[i] += bsum[blockIdx.x];
}

// ---------------- CSR fill: packed (col, dinv[src]) 8B record ----------------
__global__ void fill_kernel(const int* __restrict__ src, const int* __restrict__ dst,
                            const int* __restrict__ rowptr, int* __restrict__ fill,
                            Edge* __restrict__ edges, const float* __restrict__ dinv, int E) {
    int e = blockIdx.x * blockDim.x + threadIdx.x;
    if (e < E) {
        int d = dst[e];
        int s = src[e];
        int p = atomicAdd(&fill[d], 1);
        Edge t;
        t.c = s;
        t.d = dinv[s];
        edges[rowptr[d] + p] = t;   // one 8B store per edge
    }
}

// ---------------- GEMM m = x @ W0 (layer 0 only; 8 rows/wave) ----------------
template <int K>
__global__ __launch_bounds__(256) void gemm_kernel(const float* __restrict__ h,
                                                   const float* __restrict__ W,
                                                   float* __restrict__ m, int N) {
    __shared__ float Ws[K * 64];
    for (int i = threadIdx.x; i < K * 64; i += 256) Ws[i] = W[i];
    __syncthreads();
    const int ROWS = 8;
    int wid = (blockIdx.x * 256 + threadIdx.x) >> 6;
    int lane = threadIdx.x & 63;
    long row0 = (long)wid * ROWS;
    if (row0 >= N) return;
    const float* hr = h + row0 * K + lane;

    float hv[ROWS][K / 64];
#pragma unroll
    for (int r = 0; r < ROWS; ++r)
#pragma unroll
        for (int q = 0; q < K / 64; ++q)
            hv[r][q] = hr[(size_t)r * K + q * 64];

    float acc[ROWS];
#pragma unroll
    for (int r = 0; r < ROWS; ++r) acc[r] = 0.0f;

#pragma unroll
    for (int k = 0; k < K; ++k) {
        float wv = Ws[k * 64 + lane];
#pragma unroll
        for (int r = 0; r < ROWS; ++r) {
            unsigned hb = __builtin_amdgcn_readlane(__float_as_uint(hv[r][k >> 6]), k & 63);
            acc[r] += __uint_as_float(hb) * wv;
        }
    }

    float* mo = m + row0 * 64 + lane;
#pragma unroll
    for (int r = 0; r < ROWS; ++r) mo[r * 64] = acc[r];
}

// Gather-aggregate for one node (wave): a = di*m[self] + sum_e d_e * m[c_e].
// wid is wave-uniform (readfirstlane) so edge records load as scalar (s_load);
// unroll-8 gives 8 outstanding 256B vector gathers per wave (MLP).
__device__ __forceinline__ float gather_agg(const float* __restrict__ m,
                                            const Edge* __restrict__ ep, int n,
                                            float self_term, int lane) {
    float a = self_term;
    int e = 0;
    for (; e + 8 <= n; e += 8) {
        Edge E0 = ep[e + 0], E1 = ep[e + 1], E2 = ep[e + 2], E3 = ep[e + 3];
        Edge E4 = ep[e + 4], E5 = ep[e + 5], E6 = ep[e + 6], E7 = ep[e + 7];
        float v0 = m[(size_t)E0.c * 64 + lane];
        float v1 = m[(size_t)E1.c * 64 + lane];
        float v2 = m[(size_t)E2.c * 64 + lane];
        float v3 = m[(size_t)E3.c * 64 + lane];
        float v4 = m[(size_t)E4.c * 64 + lane];
        float v5 = m[(size_t)E5.c * 64 + lane];
        float v6 = m[(size_t)E6.c * 64 + lane];
        float v7 = m[(size_t)E7.c * 64 + lane];
        a += E0.d * v0; a += E1.d * v1; a += E2.d * v2; a += E3.d * v3;
        a += E4.d * v4; a += E5.d * v5; a += E6.d * v6; a += E7.d * v7;
    }
    for (; e < n; ++e) {
        Edge Ee = ep[e];
        a += Ee.d * m[(size_t)Ee.c * 64 + lane];
    }
    return a;
}

// ---------------- layer-0 aggregation: h1 = relu(di*a + b) ----------------
__global__ __launch_bounds__(256) void agg0_kernel(const float* __restrict__ m,
                                                   const int* __restrict__ rowptr,
                                                   const Edge* __restrict__ edges,
                                                   const float* __restrict__ dinv,
                                                   const float* __restrict__ bias,
                                                   float* __restrict__ hout, int N, int E) {
    int wid = __builtin_amdgcn_readfirstlane((blockIdx.x * 256 + threadIdx.x) >> 6);
    int lane = threadIdx.x & 63;
    if (wid >= N) return;
    int r0 = rowptr[wid];
    int r1 = (wid + 1 < N) ? rowptr[wid + 1] : E;
    float di = dinv[wid];
    float self = di * m[(size_t)wid * 64 + lane];
    float a = gather_agg(m, edges + r0, r1 - r0, self, lane);
    hout[(size_t)wid * 64 + lane] = fmaxf(di * a + bias[lane], 0.0f);
}

// ---------------- fused layer: h' = relu((A h) W + b)  (layers 1..9) ----------------
__global__ __launch_bounds__(256) void fused_kernel(const float* __restrict__ h,
                                                    const int* __restrict__ rowptr,
                                                    const Edge* __restrict__ edges,
                                                    const float* __restrict__ dinv,
                                                    const float* __restrict__ W,
                                                    const float* __restrict__ bias,
                                                    float* __restrict__ hout, int N, int E) {
    __shared__ float Ws[64 * 64];
    for (int i = threadIdx.x; i < 64 * 64; i += 256) Ws[i] = W[i];
    __syncthreads();

    int wid = __builtin_amdgcn_readfirstlane((blockIdx.x * 256 + threadIdx.x) >> 6);
    int lane = threadIdx.x & 63;
    if (wid >= N) return;
    int r0 = rowptr[wid];
    int r1 = (wid + 1 < N) ? rowptr[wid + 1] : E;
    float di = dinv[wid];
    float self = di * h[(size_t)wid * 64 + lane];
    float a = gather_agg(h, edges + r0, r1 - r0, self, lane);
    float g = di * a;   // aggregated channel value, lane = input channel k

    // in-wave GEMM: out[j=lane] = sum_k g[k] * W[k][j] + b[j]
    float acc = bias[lane];
#pragma unroll
    for (int k = 0; k < 64; ++k) {
        unsigned gb = __builtin_amdgcn_readlane(__float_as_uint(g), k);
        acc += __uint_as_float(gb) * Ws[k * 64 + lane];
    }
    hout[(size_t)wid * 64 + lane] = fmaxf(acc, 0.0f);
}

// ---------------- pooling: segment sum over sorted batch ids ----------------
__global__ __launch_bounds__(256) void pool_kernel(const float* __restrict__ h,
                                                   const int* __restrict__ batch,
                                                   float* __restrict__ gpool, int N) {
    const int NPW = 32;  // nodes per wave
    int wid = (blockIdx.x * 256 + threadIdx.x) >> 6;
    int lane = threadIdx.x & 63;
    int i0 = wid * NPW;
    if (i0 >= N) return;
    int i1 = min(i0 + NPW, N);
    int curg = batch[i0];
    float acc = 0.0f;
    for (int i = i0; i < i1; ++i) {
        int g = batch[i];
        if (g != curg) {
            atomicAdd(&gpool[curg * 64 + lane], acc);
            acc = 0.0f;
            curg = g;
        }
        acc += h[(size_t)i * 64 + lane];
    }
    atomicAdd(&gpool[curg * 64 + lane], acc);
}

// ---------------- final: out = (gpool/count) @ Wlin + blin ----------------
__global__ void final_kernel(const float* __restrict__ gpool, const int* __restrict__ gcnt,
                             const float* __restrict__ Wlin, const float* __restrict__ blin,
                             float* __restrict__ out) {
    int t = threadIdx.x;
    if (t >= NGRAPH * COUT) return;
    int g = t / COUT, o = t - g * COUT;
    float c = (float)gcnt[g];
    if (c < 1.0f) c = 1.0f;
    float s = 0.0f;
    for (int k = 0; k < 64; ++k) s += gpool[g * 64 + k] * Wlin[k * COUT + o];
    out[t] = s / c + blin[o];
}

extern "C" void kernel_launch(void* const* d_in, const int* in_sizes, int n_in,
                              void* d_out, int out_size, void* d_ws, size_t ws_size,
                              hipStream_t stream) {
    const float* x    = (const float*)d_in[0];
    const int*   ei   = (const int*)d_in[1];
    const int*   batch= (const int*)d_in[2];
    const float* W0   = (const float*)d_in[3];
    const float* b0   = (const float*)d_in[4];
    const float* Ws   = (const float*)d_in[5];
    const float* bs   = (const float*)d_in[6];
    const float* Wlin = (const float*)d_in[7];
    const float* blin = (const float*)d_in[8];
    float* out = (float*)d_out;

    const int N = NNODES, E = NEDGES;
    const int* srcp = ei;          // edge_index[0]
    const int* dstp = ei + E;      // edge_index[1]

    char* w = (char*)d_ws;
    int*   cnt    = (int*)w;   w += (size_t)N * 4;
    int*   fill   = (int*)w;   w += (size_t)N * 4;
    float* gpool  = (float*)w; w += (size_t)NGRAPH * 64 * 4;
    size_t zero_bytes = (size_t)(w - (char*)d_ws);
    int*   gcnt   = (int*)w;   w += (size_t)NGRAPH * 4;
    int*   bsum   = (int*)w;   w += (size_t)512 * 4;
    float* dinv   = (float*)w; w += (size_t)N * 4;
    int*   rowptr = (int*)w;   w += (size_t)N * 4;
    Edge*  edges  = (Edge*)w;  w += (size_t)E * 8;
    float* bufA   = (float*)w; w += (size_t)N * 64 * 4;
    float* bufB   = (float*)w; w += (size_t)N * 64 * 4;

    hipMemsetAsync(d_ws, 0, zero_bytes, stream);

    int eblocks = (E + 255) / 256;
    int nblocks = (N + 255) / 256;   // 391, fits scan_b's 512-thread block

    count_kernel<<<eblocks, 256, 0, stream>>>(dstp, cnt, E);
    dinv_kernel<<<nblocks, 256, 0, stream>>>(cnt, dinv, N);
    gcnt_kernel<<<1, 128, 0, stream>>>(batch, gcnt, N);
    scan_a<<<nblocks, 256, 0, stream>>>(cnt, rowptr, bsum, N);
    scan_b<<<1, 512, 0, stream>>>(bsum, nblocks);
    scan_c<<<nblocks, 256, 0, stream>>>(rowptr, bsum, N);
    fill_kernel<<<eblocks, 256, 0, stream>>>(srcp, dstp, rowptr, fill, edges, dinv, E);

    int gemmblocks = (N + 31) / 32;  // 8 rows/wave, 4 waves/block
    int aggblocks  = (N + 3) / 4;    // wave per node, 4 waves/block

    // layer 0: m0 = x @ W0 (K=128), then aggregate
    gemm_kernel<128><<<gemmblocks, 256, 0, stream>>>(x, W0, bufB, N);
    agg0_kernel<<<aggblocks, 256, 0, stream>>>(bufB, rowptr, edges, dinv, b0, bufA, N, E);

    // layers 1..9 fused: h' = relu((A h) W + b)
    float* hin = bufA;
    float* hout = bufB;
    for (int l = 0; l < NSTACK; ++l) {
        fused_kernel<<<aggblocks, 256, 0, stream>>>(hin, rowptr, edges, dinv,
                                                    Ws + (size_t)l * 64 * 64,
                                                    bs + (size_t)l * 64, hout, N, E);
        float* t = hin; hin = hout; hout = t;
    }
    // final h is in `hin` after the swap

    int pwaves = (N + 31) / 32;
    int pblocks = (pwaves + 3) / 4;
    pool_kernel<<<pblocks, 256, 0, stream>>>(hin, batch, gpool, N);
    final_kernel<<<1, 896, 0, stream>>>(gpool, gcnt, Wlin, blin, out);
}

// Round 5
// 998.851 us; speedup vs baseline: 2.6409x; 1.1123x over previous
//
#include <hip/hip_runtime.h>

#define NNODES 100000
#define NEDGES 1600000
#define NGRAPH 128
#define CIN 128
#define CH 64
#define COUT 7
#define NSTACK 9

struct alignas(8) Edge { int c; float d; };

// ---------------- degree count ----------------
__global__ void count_kernel(const int* __restrict__ dst, int* __restrict__ cnt, int E) {
    int e = blockIdx.x * blockDim.x + threadIdx.x;
    if (e < E) atomicAdd(&cnt[dst[e]], 1);
}

// ---------------- dinv (streaming only, no atomics) ----------------
__global__ void dinv_kernel(const int* __restrict__ cnt, float* __restrict__ dinv, int N) {
    int i = blockIdx.x * blockDim.x + threadIdx.x;
    if (i < N) {
        dinv[i] = 1.0f / sqrtf((float)(cnt[i] + 1));  // +1 self-loop, always >= 1
    }
}

// ---------------- per-graph node counts via binary search (batch is sorted) ----------------
__global__ void gcnt_kernel(const int* __restrict__ batch, int* __restrict__ gcnt, int N) {
    int g = threadIdx.x;
    if (g >= NGRAPH) return;
    auto lb = [&](int v) {
        int lo = 0, hi = N;
        while (lo < hi) {
            int mid = (lo + hi) >> 1;
            if (batch[mid] < v) lo = mid + 1; else hi = mid;
        }
        return lo;
    };
    gcnt[g] = lb(g + 1) - lb(g);
}

// ---------------- exclusive scan (3-phase) ----------------
__global__ void scan_a(const int* __restrict__ cnt, int* __restrict__ rowptr,
                       int* __restrict__ bsum, int N) {
    __shared__ int s[256];
    int i = blockIdx.x * 256 + threadIdx.x;
    int v = (i < N) ? cnt[i] : 0;
    s[threadIdx.x] = v;
    __syncthreads();
    for (int d = 1; d < 256; d <<= 1) {
        int t = (threadIdx.x >= d) ? s[threadIdx.x - d] : 0;
        __syncthreads();
        s[threadIdx.x] += t;
        __syncthreads();
    }
    if (i < N) rowptr[i] = s[threadIdx.x] - v;   // exclusive
    if (threadIdx.x == 255) bsum[blockIdx.x] = s[255];
}

__global__ void scan_b(int* __restrict__ bsum, int nb) {
    __shared__ int s[512];
    int v = (threadIdx.x < nb) ? bsum[threadIdx.x] : 0;
    s[threadIdx.x] = v;
    __syncthreads();
    for (int d = 1; d < 512; d <<= 1) {
        int t = (threadIdx.x >= (unsigned)d) ? s[threadIdx.x - d] : 0;
        __syncthreads();
        s[threadIdx.x] += t;
        __syncthreads();
    }
    if (threadIdx.x < nb) bsum[threadIdx.x] = s[threadIdx.x] - v;  // exclusive
}

__global__ void scan_c(int* __restrict__ rowptr, const int* __restrict__ bsum, int N) {
    int i = blockIdx.x * 256 + threadIdx.x;
    if (i < N) rowptr[i] += bsum[blockIdx.x];
}

// ---------------- CSR fill: packed (col, dinv[src]) 8B record ----------------
__global__ void fill_kernel(const int* __restrict__ src, const int* __restrict__ dst,
                            const int* __restrict__ rowptr, int* __restrict__ fill,
                            Edge* __restrict__ edges, const float* __restrict__ dinv, int E) {
    int e = blockIdx.x * blockDim.x + threadIdx.x;
    if (e < E) {
        int d = dst[e];
        int s = src[e];
        int p = atomicAdd(&fill[d], 1);
        Edge t;
        t.c = s;
        t.d = dinv[s];
        edges[rowptr[d] + p] = t;   // one 8B store per edge
    }
}

// ---------------- GEMM m = x @ W0 (layer 0 only; 8 rows/wave) ----------------
template <int K>
__global__ __launch_bounds__(256) void gemm_kernel(const float* __restrict__ h,
                                                   const float* __restrict__ W,
                                                   float* __restrict__ m, int N) {
    __shared__ float Ws[K * 64];
    for (int i = threadIdx.x; i < K * 64; i += 256) Ws[i] = W[i];
    __syncthreads();
    const int ROWS = 8;
    int wid = (blockIdx.x * 256 + threadIdx.x) >> 6;
    int lane = threadIdx.x & 63;
    long row0 = (long)wid * ROWS;
    if (row0 >= N) return;
    const float* hr = h + row0 * K + lane;

    float hv[ROWS][K / 64];
#pragma unroll
    for (int r = 0; r < ROWS; ++r)
#pragma unroll
        for (int q = 0; q < K / 64; ++q)
            hv[r][q] = hr[(size_t)r * K + q * 64];

    float acc[ROWS];
#pragma unroll
    for (int r = 0; r < ROWS; ++r) acc[r] = 0.0f;

#pragma unroll
    for (int k = 0; k < K; ++k) {
        float wv = Ws[k * 64 + lane];
#pragma unroll
        for (int r = 0; r < ROWS; ++r) {
            unsigned hb = __builtin_amdgcn_readlane(__float_as_uint(hv[r][k >> 6]), k & 63);
            acc[r] += __uint_as_float(hb) * wv;
        }
    }

    float* mo = m + row0 * 64 + lane;
#pragma unroll
    for (int r = 0; r < ROWS; ++r) mo[r * 64] = acc[r];
}

// Gather-aggregate for one node (wave): a = self + sum_e d_e * m[c_e].
// Edge records are wave-uniform (s_load); unroll-16 issues up to 16
// outstanding 256B vector gathers per wave before the dependent FMAs
// (avg degree = 16 -> most nodes finish the gather in one latency round).
__device__ __forceinline__ float gather_agg(const float* __restrict__ m,
                                            const Edge* __restrict__ ep, int n,
                                            float self_term, int lane) {
    float a = self_term;
    int e = 0;
    for (; e + 16 <= n; e += 16) {
        Edge Ed[16];
        float v[16];
#pragma unroll
        for (int u = 0; u < 16; ++u) Ed[u] = ep[e + u];
#pragma unroll
        for (int u = 0; u < 16; ++u) v[u] = m[(size_t)Ed[u].c * 64 + lane];
#pragma unroll
        for (int u = 0; u < 16; ++u) a += Ed[u].d * v[u];
    }
    for (; e + 4 <= n; e += 4) {
        Edge Ed[4];
        float v[4];
#pragma unroll
        for (int u = 0; u < 4; ++u) Ed[u] = ep[e + u];
#pragma unroll
        for (int u = 0; u < 4; ++u) v[u] = m[(size_t)Ed[u].c * 64 + lane];
#pragma unroll
        for (int u = 0; u < 4; ++u) a += Ed[u].d * v[u];
    }
    for (; e < n; ++e) {
        Edge Ee = ep[e];
        a += Ee.d * m[(size_t)Ee.c * 64 + lane];
    }
    return a;
}

// ---------------- layer-0 aggregation: h1 = relu(di*a + b) ----------------
__global__ __launch_bounds__(256) void agg0_kernel(const float* __restrict__ m,
                                                   const int* __restrict__ rowptr,
                                                   const Edge* __restrict__ edges,
                                                   const float* __restrict__ dinv,
                                                   const float* __restrict__ bias,
                                                   float* __restrict__ hout, int N, int E) {
    int wid = __builtin_amdgcn_readfirstlane((blockIdx.x * 256 + threadIdx.x) >> 6);
    int lane = threadIdx.x & 63;
    if (wid >= N) return;
    int r0 = rowptr[wid];
    int r1 = (wid + 1 < N) ? rowptr[wid + 1] : E;
    float di = dinv[wid];
    float self = di * m[(size_t)wid * 64 + lane];
    float a = gather_agg(m, edges + r0, r1 - r0, self, lane);
    hout[(size_t)wid * 64 + lane] = fmaxf(di * a + bias[lane], 0.0f);
}

// ---------------- fused layer: h' = relu((A h) W + b)  (layers 1..9) ----------------
// W is staged to LDS but the barrier is deferred until after the gather:
// the staging stores drain under the gather's memory latency.
__global__ __launch_bounds__(256) void fused_kernel(const float* __restrict__ h,
                                                    const int* __restrict__ rowptr,
                                                    const Edge* __restrict__ edges,
                                                    const float* __restrict__ dinv,
                                                    const float* __restrict__ W,
                                                    const float* __restrict__ bias,
                                                    float* __restrict__ hout, int N, int E) {
    __shared__ float Ws[64 * 64];
    {
        const float4* W4 = (const float4*)W;
        float4* Ws4 = (float4*)Ws;
        for (int i = threadIdx.x; i < 64 * 16; i += 256) Ws4[i] = W4[i];
    }

    int wid = __builtin_amdgcn_readfirstlane((blockIdx.x * 256 + threadIdx.x) >> 6);
    int lane = threadIdx.x & 63;
    bool active = (wid < N);
    float g = 0.0f;
    if (active) {
        int r0 = rowptr[wid];
        int r1 = (wid + 1 < N) ? rowptr[wid + 1] : E;
        float di = dinv[wid];
        float self = di * h[(size_t)wid * 64 + lane];
        float a = gather_agg(h, edges + r0, r1 - r0, self, lane);
        g = di * a;   // aggregated channel value, lane = input channel k
    }

    __syncthreads();   // W staging visible; all waves (incl. inactive) arrive

    if (active) {
        // in-wave GEMM: out[j=lane] = sum_k g[k] * W[k][j] + b[j]
        float acc = bias[lane];
#pragma unroll
        for (int k = 0; k < 64; ++k) {
            unsigned gb = __builtin_amdgcn_readlane(__float_as_uint(g), k);
            acc += __uint_as_float(gb) * Ws[k * 64 + lane];
        }
        hout[(size_t)wid * 64 + lane] = fmaxf(acc, 0.0f);
    }
}

// ---------------- pooling: segment sum over sorted batch ids ----------------
__global__ __launch_bounds__(256) void pool_kernel(const float* __restrict__ h,
                                                   const int* __restrict__ batch,
                                                   float* __restrict__ gpool, int N) {
    const int NPW = 32;  // nodes per wave
    int wid = (blockIdx.x * 256 + threadIdx.x) >> 6;
    int lane = threadIdx.x & 63;
    int i0 = wid * NPW;
    if (i0 >= N) return;
    int i1 = min(i0 + NPW, N);
    int curg = batch[i0];
    float acc = 0.0f;
    for (int i = i0; i < i1; ++i) {
        int g = batch[i];
        if (g != curg) {
            atomicAdd(&gpool[curg * 64 + lane], acc);
            acc = 0.0f;
            curg = g;
        }
        acc += h[(size_t)i * 64 + lane];
    }
    atomicAdd(&gpool[curg * 64 + lane], acc);
}

// ---------------- final: out = (gpool/count) @ Wlin + blin ----------------
__global__ void final_kernel(const float* __restrict__ gpool, const int* __restrict__ gcnt,
                             const float* __restrict__ Wlin, const float* __restrict__ blin,
                             float* __restrict__ out) {
    int t = threadIdx.x;
    if (t >= NGRAPH * COUT) return;
    int g = t / COUT, o = t - g * COUT;
    float c = (float)gcnt[g];
    if (c < 1.0f) c = 1.0f;
    float s = 0.0f;
    for (int k = 0; k < 64; ++k) s += gpool[g * 64 + k] * Wlin[k * COUT + o];
    out[t] = s / c + blin[o];
}

extern "C" void kernel_launch(void* const* d_in, const int* in_sizes, int n_in,
                              void* d_out, int out_size, void* d_ws, size_t ws_size,
                              hipStream_t stream) {
    const float* x    = (const float*)d_in[0];
    const int*   ei   = (const int*)d_in[1];
    const int*   batch= (const int*)d_in[2];
    const float* W0   = (const float*)d_in[3];
    const float* b0   = (const float*)d_in[4];
    const float* Ws   = (const float*)d_in[5];
    const float* bs   = (const float*)d_in[6];
    const float* Wlin = (const float*)d_in[7];
    const float* blin = (const float*)d_in[8];
    float* out = (float*)d_out;

    const int N = NNODES, E = NEDGES;
    const int* srcp = ei;          // edge_index[0]
    const int* dstp = ei + E;      // edge_index[1]

    char* w = (char*)d_ws;
    int*   cnt    = (int*)w;   w += (size_t)N * 4;
    int*   fill   = (int*)w;   w += (size_t)N * 4;
    float* gpool  = (float*)w; w += (size_t)NGRAPH * 64 * 4;
    size_t zero_bytes = (size_t)(w - (char*)d_ws);
    int*   gcnt   = (int*)w;   w += (size_t)NGRAPH * 4;
    int*   bsum   = (int*)w;   w += (size_t)512 * 4;
    float* dinv   = (float*)w; w += (size_t)N * 4;
    int*   rowptr = (int*)w;   w += (size_t)N * 4;
    Edge*  edges  = (Edge*)w;  w += (size_t)E * 8;
    float* bufA   = (float*)w; w += (size_t)N * 64 * 4;
    float* bufB   = (float*)w; w += (size_t)N * 64 * 4;

    hipMemsetAsync(d_ws, 0, zero_bytes, stream);

    int eblocks = (E + 255) / 256;
    int nblocks = (N + 255) / 256;   // 391, fits scan_b's 512-thread block

    count_kernel<<<eblocks, 256, 0, stream>>>(dstp, cnt, E);
    dinv_kernel<<<nblocks, 256, 0, stream>>>(cnt, dinv, N);
    gcnt_kernel<<<1, 128, 0, stream>>>(batch, gcnt, N);
    scan_a<<<nblocks, 256, 0, stream>>>(cnt, rowptr, bsum, N);
    scan_b<<<1, 512, 0, stream>>>(bsum, nblocks);
    scan_c<<<nblocks, 256, 0, stream>>>(rowptr, bsum, N);
    fill_kernel<<<eblocks, 256, 0, stream>>>(srcp, dstp, rowptr, fill, edges, dinv, E);

    int gemmblocks = (N + 31) / 32;  // 8 rows/wave, 4 waves/block
    int aggblocks  = (N + 3) / 4;    // wave per node, 4 waves/block

    // layer 0: m0 = x @ W0 (K=128), then aggregate
    gemm_kernel<128><<<gemmblocks, 256, 0, stream>>>(x, W0, bufB, N);
    agg0_kernel<<<aggblocks, 256, 0, stream>>>(bufB, rowptr, edges, dinv, b0, bufA, N, E);

    // layers 1..9 fused: h' = relu((A h) W + b)
    float* hin = bufA;
    float* hout = bufB;
    for (int l = 0; l < NSTACK; ++l) {
        fused_kernel<<<aggblocks, 256, 0, stream>>>(hin, rowptr, edges, dinv,
                                                    Ws + (size_t)l * 64 * 64,
                                                    bs + (size_t)l * 64, hout, N, E);
        float* t = hin; hin = hout; hout = t;
    }
    // final h is in `hin` after the swap

    int pwaves = (N + 31) / 32;
    int pblocks = (pwaves + 3) / 4;
    pool_kernel<<<pblocks, 256, 0, stream>>>(hin, batch, gpool, N);
    final_kernel<<<1, 896, 0, stream>>>(gpool, gcnt, Wlin, blin, out);
}

// Round 6
// 976.727 us; speedup vs baseline: 2.7007x; 1.0227x over previous
//
#include <hip/hip_runtime.h>

#define NNODES 100000
#define NEDGES 1600000
#define NGRAPH 128
#define CIN 128
#define CH 64
#define COUT 7
#define NSTACK 9

struct alignas(8) Edge { int c; float d; };

// ---------------- merged: degree count (atomics) + layer-0 GEMM ----------------
// Independent work co-scheduled in one launch to overlap atomic latency with
// the VALU-heavy GEMM (single-stream kernels never overlap otherwise).
template <int K>
__global__ __launch_bounds__(256) void count_gemm_kernel(const int* __restrict__ dst,
                                                         int* __restrict__ cnt, int E,
                                                         const float* __restrict__ h,
                                                         const float* __restrict__ W,
                                                         float* __restrict__ m, int N,
                                                         int countBlocks) {
    __shared__ float Ws[K * 64];
    if (blockIdx.x < (unsigned)countBlocks) {
        int e = blockIdx.x * 256 + threadIdx.x;
        if (e < E) atomicAdd(&cnt[dst[e]], 1);
        return;
    }
    // ---- GEMM part: 8 rows/wave ----
    int gb = blockIdx.x - countBlocks;
    for (int i = threadIdx.x; i < K * 64; i += 256) Ws[i] = W[i];
    __syncthreads();
    const int ROWS = 8;
    int wid = (gb * 256 + (int)threadIdx.x) >> 6;
    int lane = threadIdx.x & 63;
    long row0 = (long)wid * ROWS;
    if (row0 >= N) return;
    const float* hr = h + row0 * K + lane;

    float hv[ROWS][K / 64];
#pragma unroll
    for (int r = 0; r < ROWS; ++r)
#pragma unroll
        for (int q = 0; q < K / 64; ++q)
            hv[r][q] = hr[(size_t)r * K + q * 64];

    float acc[ROWS];
#pragma unroll
    for (int r = 0; r < ROWS; ++r) acc[r] = 0.0f;

#pragma unroll
    for (int k = 0; k < K; ++k) {
        float wv = Ws[k * 64 + lane];
#pragma unroll
        for (int r = 0; r < ROWS; ++r) {
            unsigned hb = __builtin_amdgcn_readlane(__float_as_uint(hv[r][k >> 6]), k & 63);
            acc[r] += __uint_as_float(hb) * wv;
        }
    }

    float* mo = m + row0 * 64 + lane;
#pragma unroll
    for (int r = 0; r < ROWS; ++r) mo[r * 64] = acc[r];
}

// ---------------- merged: dinv + per-graph counts ----------------
__global__ void dinv_gcnt_kernel(const int* __restrict__ cnt, float* __restrict__ dinv,
                                 const int* __restrict__ batch, int* __restrict__ gcnt,
                                 int N, int nblocks) {
    if ((int)blockIdx.x == nblocks) {
        int g = threadIdx.x;
        if (g >= NGRAPH) return;
        auto lb = [&](int v) {
            int lo = 0, hi = N;
            while (lo < hi) {
                int mid = (lo + hi) >> 1;
                if (batch[mid] < v) lo = mid + 1; else hi = mid;
            }
            return lo;
        };
        gcnt[g] = lb(g + 1) - lb(g);
        return;
    }
    int i = blockIdx.x * 256 + threadIdx.x;
    if (i < N) dinv[i] = 1.0f / sqrtf((float)(cnt[i] + 1));  // +1 self-loop
}

// ---------------- exclusive scan (3-phase) ----------------
__global__ void scan_a(const int* __restrict__ cnt, int* __restrict__ rowptr,
                       int* __restrict__ bsum, int N) {
    __shared__ int s[256];
    int i = blockIdx.x * 256 + threadIdx.x;
    int v = (i < N) ? cnt[i] : 0;
    s[threadIdx.x] = v;
    __syncthreads();
    for (int d = 1; d < 256; d <<= 1) {
        int t = (threadIdx.x >= d) ? s[threadIdx.x - d] : 0;
        __syncthreads();
        s[threadIdx.x] += t;
        __syncthreads();
    }
    if (i < N) rowptr[i] = s[threadIdx.x] - v;   // exclusive
    if (threadIdx.x == 255) bsum[blockIdx.x] = s[255];
}

__global__ void scan_b(int* __restrict__ bsum, int nb) {
    __shared__ int s[512];
    int v = (threadIdx.x < nb) ? bsum[threadIdx.x] : 0;
    s[threadIdx.x] = v;
    __syncthreads();
    for (int d = 1; d < 512; d <<= 1) {
        int t = (threadIdx.x >= (unsigned)d) ? s[threadIdx.x - d] : 0;
        __syncthreads();
        s[threadIdx.x] += t;
        __syncthreads();
    }
    if (threadIdx.x < nb) bsum[threadIdx.x] = s[threadIdx.x] - v;  // exclusive
}

__global__ void scan_c(int* __restrict__ rowptr, const int* __restrict__ bsum, int N) {
    int i = blockIdx.x * 256 + threadIdx.x;
    if (i < N) rowptr[i] += bsum[blockIdx.x];
}

// ---------------- CSR fill, XCD-routed ----------------
// Block class (blockIdx&7) ~ XCD id (round-robin heuristic). Class c only
// writes edges of 16-node groups with (dst>>4)&7==c, so each ~2KB CSR region
// is written by a single XCD: its L2 accumulates FULL dirty lines -> clean
// 64B writebacks (vs 8x partial-line amplification). Costs 8 filtered sweeps
// of the LLC-resident dst[] stream. Correct under any blockIdx->XCD mapping.
__global__ __launch_bounds__(256) void fill_sweep_kernel(const int* __restrict__ src,
                                                         const int* __restrict__ dst,
                                                         const int* __restrict__ rowptr,
                                                         int* __restrict__ fill,
                                                         Edge* __restrict__ edges,
                                                         const float* __restrict__ dinv, int E) {
    int cls = blockIdx.x & 7;
    int bic = blockIdx.x >> 3;            // block index within class
    int bpc = gridDim.x >> 3;             // blocks per class
    for (int e = bic * 256 + (int)threadIdx.x; e < E; e += bpc * 256) {
        int d = dst[e];
        if (((d >> 4) & 7) == cls) {
            int s = src[e];
            int p = atomicAdd(&fill[d], 1);
            Edge t;
            t.c = s;
            t.d = dinv[s];
            edges[rowptr[d] + p] = t;
        }
    }
}

// Gather-aggregate for one node (wave): a = self + sum_e d_e * m[c_e].
__device__ __forceinline__ float gather_agg(const float* __restrict__ m,
                                            const Edge* __restrict__ ep, int n,
                                            float a, int lane) {
    int e = 0;
    for (; e + 16 <= n; e += 16) {
        Edge Ed[16];
        float v[16];
#pragma unroll
        for (int u = 0; u < 16; ++u) Ed[u] = ep[e + u];
#pragma unroll
        for (int u = 0; u < 16; ++u) v[u] = m[(size_t)Ed[u].c * 64 + lane];
#pragma unroll
        for (int u = 0; u < 16; ++u) a += Ed[u].d * v[u];
    }
    for (; e + 4 <= n; e += 4) {
        Edge Ed[4];
        float v[4];
#pragma unroll
        for (int u = 0; u < 4; ++u) Ed[u] = ep[e + u];
#pragma unroll
        for (int u = 0; u < 4; ++u) v[u] = m[(size_t)Ed[u].c * 64 + lane];
#pragma unroll
        for (int u = 0; u < 4; ++u) a += Ed[u].d * v[u];
    }
    for (; e < n; ++e) {
        Edge Ee = ep[e];
        a += Ee.d * m[(size_t)Ee.c * 64 + lane];
    }
    return a;
}

// ---------------- layer-0 aggregation: h1 = relu(di*a + b) ----------------
__global__ __launch_bounds__(256) void agg0_kernel(const float* __restrict__ m,
                                                   const int* __restrict__ rowptr,
                                                   const Edge* __restrict__ edges,
                                                   const float* __restrict__ dinv,
                                                   const float* __restrict__ bias,
                                                   float* __restrict__ hout, int N, int E) {
    int wid = __builtin_amdgcn_readfirstlane((blockIdx.x * 256 + threadIdx.x) >> 6);
    int lane = threadIdx.x & 63;
    if (wid >= N) return;
    int r0 = rowptr[wid];
    int r1 = (wid + 1 < N) ? rowptr[wid + 1] : E;
    float di = dinv[wid];
    float self = di * m[(size_t)wid * 64 + lane];
    float a = gather_agg(m, edges + r0, r1 - r0, self, lane);
    hout[(size_t)wid * 64 + lane] = fmaxf(di * a + bias[lane], 0.0f);
}

// ---------------- fused layer, 2 nodes per wave: h' = relu((A h) W + b) ----------------
// Each wave owns nodes {2*wid, 2*wid+1}. Gather keeps up to 32 loads in
// flight; the in-wave GEMM reads each W[k][lane] from LDS ONCE and applies it
// to both nodes (halves LDS traffic + readlane/issue overhead per node).
// W staging barrier deferred until after the gather.
__global__ __launch_bounds__(256) void fused_kernel(const float* __restrict__ h,
                                                    const int* __restrict__ rowptr,
                                                    const Edge* __restrict__ edges,
                                                    const float* __restrict__ dinv,
                                                    const float* __restrict__ W,
                                                    const float* __restrict__ bias,
                                                    float* __restrict__ hout, int N, int E) {
    __shared__ float Ws[64 * 64];
    {
        const float4* W4 = (const float4*)W;
        float4* Ws4 = (float4*)Ws;
        for (int i = threadIdx.x; i < 64 * 16; i += 256) Ws4[i] = W4[i];
    }

    int wid = __builtin_amdgcn_readfirstlane((blockIdx.x * 256 + threadIdx.x) >> 6);
    int lane = threadIdx.x & 63;
    int nodeA = wid * 2;
    int nodeB = nodeA + 1;
    bool actA = (nodeA < N);
    bool actB = (nodeB < N);
    float gA = 0.0f, gB = 0.0f;

    if (actA) {
        int r0A = rowptr[nodeA];
        int r1A = rowptr[nodeB];   // nodeB==nodeA+1; valid since nodeA<N
        int r1B = 0, r0B = 0;
        float diA = dinv[nodeA], diB = 0.0f;
        float aA = diA * h[(size_t)nodeA * 64 + lane];
        float aB = 0.0f;
        if (actB) {
            r0B = r1A;
            r1B = (nodeB + 1 < N) ? rowptr[nodeB + 1] : E;
            diB = dinv[nodeB];
            aB = diB * h[(size_t)nodeB * 64 + lane];
        }
        const Edge* epA = edges + r0A;
        const Edge* epB = edges + r0B;
        int nA = r1A - r0A;
        int nB = r1B - r0B;
        int eA = 0, eB = 0;
        // combined rounds: 32 gathers in flight
        while (eA + 16 <= nA && eB + 16 <= nB) {
            Edge EdA[16], EdB[16];
            float vA[16], vB[16];
#pragma unroll
            for (int u = 0; u < 16; ++u) EdA[u] = epA[eA + u];
#pragma unroll
            for (int u = 0; u < 16; ++u) EdB[u] = epB[eB + u];
#pragma unroll
            for (int u = 0; u < 16; ++u) vA[u] = h[(size_t)EdA[u].c * 64 + lane];
#pragma unroll
            for (int u = 0; u < 16; ++u) vB[u] = h[(size_t)EdB[u].c * 64 + lane];
#pragma unroll
            for (int u = 0; u < 16; ++u) { aA += EdA[u].d * vA[u]; aB += EdB[u].d * vB[u]; }
            eA += 16;
            eB += 16;
        }
        aA = gather_agg(h, epA + eA, nA - eA, aA, lane);
        if (actB) aB = gather_agg(h, epB + eB, nB - eB, aB, lane);
        gA = diA * aA;
        gB = diB * aB;
    }

    __syncthreads();   // W staging visible; all waves arrive

    if (actA) {
        float bv = bias[lane];
        float accA = bv, accB = bv;
#pragma unroll
        for (int k = 0; k < 64; ++k) {
            float wv = Ws[k * 64 + lane];
            unsigned ga = __builtin_amdgcn_readlane(__float_as_uint(gA), k);
            unsigned gb = __builtin_amdgcn_readlane(__float_as_uint(gB), k);
            accA += __uint_as_float(ga) * wv;
            accB += __uint_as_float(gb) * wv;
        }
        hout[(size_t)nodeA * 64 + lane] = fmaxf(accA, 0.0f);
        if (actB) hout[(size_t)nodeB * 64 + lane] = fmaxf(accB, 0.0f);
    }
}

// ---------------- pooling: segment sum over sorted batch ids ----------------
__global__ __launch_bounds__(256) void pool_kernel(const float* __restrict__ h,
                                                   const int* __restrict__ batch,
                                                   float* __restrict__ gpool, int N) {
    const int NPW = 32;  // nodes per wave
    int wid = (blockIdx.x * 256 + threadIdx.x) >> 6;
    int lane = threadIdx.x & 63;
    int i0 = wid * NPW;
    if (i0 >= N) return;
    int i1 = min(i0 + NPW, N);
    int curg = batch[i0];
    float acc = 0.0f;
    for (int i = i0; i < i1; ++i) {
        int g = batch[i];
        if (g != curg) {
            atomicAdd(&gpool[curg * 64 + lane], acc);
            acc = 0.0f;
            curg = g;
        }
        acc += h[(size_t)i * 64 + lane];
    }
    atomicAdd(&gpool[curg * 64 + lane], acc);
}

// ---------------- final: out = (gpool/count) @ Wlin + blin ----------------
__global__ void final_kernel(const float* __restrict__ gpool, const int* __restrict__ gcnt,
                             const float* __restrict__ Wlin, const float* __restrict__ blin,
                             float* __restrict__ out) {
    int t = threadIdx.x;
    if (t >= NGRAPH * COUT) return;
    int g = t / COUT, o = t - g * COUT;
    float c = (float)gcnt[g];
    if (c < 1.0f) c = 1.0f;
    float s = 0.0f;
    for (int k = 0; k < 64; ++k) s += gpool[g * 64 + k] * Wlin[k * COUT + o];
    out[t] = s / c + blin[o];
}

extern "C" void kernel_launch(void* const* d_in, const int* in_sizes, int n_in,
                              void* d_out, int out_size, void* d_ws, size_t ws_size,
                              hipStream_t stream) {
    const float* x    = (const float*)d_in[0];
    const int*   ei   = (const int*)d_in[1];
    const int*   batch= (const int*)d_in[2];
    const float* W0   = (const float*)d_in[3];
    const float* b0   = (const float*)d_in[4];
    const float* Ws   = (const float*)d_in[5];
    const float* bs   = (const float*)d_in[6];
    const float* Wlin = (const float*)d_in[7];
    const float* blin = (const float*)d_in[8];
    float* out = (float*)d_out;

    const int N = NNODES, E = NEDGES;
    const int* srcp = ei;          // edge_index[0]
    const int* dstp = ei + E;      // edge_index[1]

    char* w = (char*)d_ws;
    int*   cnt    = (int*)w;   w += (size_t)N * 4;
    int*   fill   = (int*)w;   w += (size_t)N * 4;
    float* gpool  = (float*)w; w += (size_t)NGRAPH * 64 * 4;
    size_t zero_bytes = (size_t)(w - (char*)d_ws);
    int*   gcnt   = (int*)w;   w += (size_t)NGRAPH * 4;
    int*   bsum   = (int*)w;   w += (size_t)512 * 4;
    float* dinv   = (float*)w; w += (size_t)N * 4;
    int*   rowptr = (int*)w;   w += (size_t)N * 4;
    Edge*  edges  = (Edge*)w;  w += (size_t)E * 8;
    float* bufA   = (float*)w; w += (size_t)N * 64 * 4;
    float* bufB   = (float*)w; w += (size_t)N * 64 * 4;

    hipMemsetAsync(d_ws, 0, zero_bytes, stream);

    int eblocks = (E + 255) / 256;   // 6250
    int nblocks = (N + 255) / 256;   // 391, fits scan_b's 512-thread block
    int gemmblocks = (N + 31) / 32;  // 3125: 8 rows/wave, 4 waves/block

    // count + layer-0 GEMM co-scheduled (independent)
    count_gemm_kernel<128><<<eblocks + gemmblocks, 256, 0, stream>>>(
        dstp, cnt, E, x, W0, bufB, N, eblocks);
    // dinv + gcnt co-scheduled
    dinv_gcnt_kernel<<<nblocks + 1, 256, 0, stream>>>(cnt, dinv, batch, gcnt, N, nblocks);
    scan_a<<<nblocks, 256, 0, stream>>>(cnt, rowptr, bsum, N);
    scan_b<<<1, 512, 0, stream>>>(bsum, nblocks);
    scan_c<<<nblocks, 256, 0, stream>>>(rowptr, bsum, N);
    fill_sweep_kernel<<<2048, 256, 0, stream>>>(srcp, dstp, rowptr, fill, edges, dinv, E);

    int aggblocks = (N + 3) / 4;          // wave per node (agg0)
    int fusedblocks = ((N + 1) / 2 + 3) / 4;  // 2 nodes per wave

    agg0_kernel<<<aggblocks, 256, 0, stream>>>(bufB, rowptr, edges, dinv, b0, bufA, N, E);

    // layers 1..9 fused: h' = relu((A h) W + b)
    float* hin = bufA;
    float* hout = bufB;
    for (int l = 0; l < NSTACK; ++l) {
        fused_kernel<<<fusedblocks, 256, 0, stream>>>(hin, rowptr, edges, dinv,
                                                      Ws + (size_t)l * 64 * 64,
                                                      bs + (size_t)l * 64, hout, N, E);
        float* t = hin; hin = hout; hout = t;
    }
    // final h is in `hin` after the swap

    int pwaves = (N + 31) / 32;
    int pblocks = (pwaves + 3) / 4;
    pool_kernel<<<pblocks, 256, 0, stream>>>(hin, batch, gpool, N);
    final_kernel<<<1, 896, 0, stream>>>(gpool, gcnt, Wlin, blin, out);
}

// Round 7
// 891.724 us; speedup vs baseline: 2.9582x; 1.0953x over previous
//
#include <hip/hip_runtime.h>
#include <hip/hip_fp16.h>

#define NNODES 100000
#define NEDGES 1600000
#define NGRAPH 128
#define CIN 128
#define CH 64
#define COUT 7
#define NSTACK 9

struct alignas(8) Edge { int c; float d; };

// ---------------- merged: degree count (atomics) + layer-0 GEMM ----------------
template <int K>
__global__ __launch_bounds__(256) void count_gemm_kernel(const int* __restrict__ dst,
                                                         int* __restrict__ cnt, int E,
                                                         const float* __restrict__ h,
                                                         const float* __restrict__ W,
                                                         __half* __restrict__ m, int N,
                                                         int countBlocks) {
    __shared__ float Ws[K * 64];
    if (blockIdx.x < (unsigned)countBlocks) {
        int e = blockIdx.x * 256 + threadIdx.x;
        if (e < E) atomicAdd(&cnt[dst[e]], 1);
        return;
    }
    // ---- GEMM part: 8 rows/wave ----
    int gb = blockIdx.x - countBlocks;
    for (int i = threadIdx.x; i < K * 64; i += 256) Ws[i] = W[i];
    __syncthreads();
    const int ROWS = 8;
    int wid = (gb * 256 + (int)threadIdx.x) >> 6;
    int lane = threadIdx.x & 63;
    long row0 = (long)wid * ROWS;
    if (row0 >= N) return;
    const float* hr = h + row0 * K + lane;

    float hv[ROWS][K / 64];
#pragma unroll
    for (int r = 0; r < ROWS; ++r)
#pragma unroll
        for (int q = 0; q < K / 64; ++q)
            hv[r][q] = hr[(size_t)r * K + q * 64];

    float acc[ROWS];
#pragma unroll
    for (int r = 0; r < ROWS; ++r) acc[r] = 0.0f;

#pragma unroll
    for (int k = 0; k < K; ++k) {
        float wv = Ws[k * 64 + lane];
#pragma unroll
        for (int r = 0; r < ROWS; ++r) {
            unsigned hb = __builtin_amdgcn_readlane(__float_as_uint(hv[r][k >> 6]), k & 63);
            acc[r] += __uint_as_float(hb) * wv;
        }
    }

    __half* mo = m + row0 * 64 + lane;
#pragma unroll
    for (int r = 0; r < ROWS; ++r) mo[r * 64] = __float2half(acc[r]);
}

// ---------------- merged: dinv + per-graph counts ----------------
__global__ void dinv_gcnt_kernel(const int* __restrict__ cnt, float* __restrict__ dinv,
                                 const int* __restrict__ batch, int* __restrict__ gcnt,
                                 int N, int nblocks) {
    if ((int)blockIdx.x == nblocks) {
        int g = threadIdx.x;
        if (g >= NGRAPH) return;
        auto lb = [&](int v) {
            int lo = 0, hi = N;
            while (lo < hi) {
                int mid = (lo + hi) >> 1;
                if (batch[mid] < v) lo = mid + 1; else hi = mid;
            }
            return lo;
        };
        gcnt[g] = lb(g + 1) - lb(g);
        return;
    }
    int i = blockIdx.x * 256 + threadIdx.x;
    if (i < N) dinv[i] = 1.0f / sqrtf((float)(cnt[i] + 1));  // +1 self-loop
}

// ---------------- exclusive scan (3-phase) ----------------
__global__ void scan_a(const int* __restrict__ cnt, int* __restrict__ rowptr,
                       int* __restrict__ bsum, int N) {
    __shared__ int s[256];
    int i = blockIdx.x * 256 + threadIdx.x;
    int v = (i < N) ? cnt[i] : 0;
    s[threadIdx.x] = v;
    __syncthreads();
    for (int d = 1; d < 256; d <<= 1) {
        int t = (threadIdx.x >= d) ? s[threadIdx.x - d] : 0;
        __syncthreads();
        s[threadIdx.x] += t;
        __syncthreads();
    }
    if (i < N) rowptr[i] = s[threadIdx.x] - v;   // exclusive
    if (threadIdx.x == 255) bsum[blockIdx.x] = s[255];
}

__global__ void scan_b(int* __restrict__ bsum, int nb) {
    __shared__ int s[512];
    int v = (threadIdx.x < nb) ? bsum[threadIdx.x] : 0;
    s[threadIdx.x] = v;
    __syncthreads();
    for (int d = 1; d < 512; d <<= 1) {
        int t = (threadIdx.x >= (unsigned)d) ? s[threadIdx.x - d] : 0;
        __syncthreads();
        s[threadIdx.x] += t;
        __syncthreads();
    }
    if (threadIdx.x < nb) bsum[threadIdx.x] = s[threadIdx.x] - v;  // exclusive
}

__global__ void scan_c(int* __restrict__ rowptr, const int* __restrict__ bsum, int N) {
    int i = blockIdx.x * 256 + threadIdx.x;
    if (i < N) rowptr[i] += bsum[blockIdx.x];
}

// ---------------- CSR fill, XCD-routed (full dirty lines per L2) ----------------
__global__ __launch_bounds__(256) void fill_sweep_kernel(const int* __restrict__ src,
                                                         const int* __restrict__ dst,
                                                         const int* __restrict__ rowptr,
                                                         int* __restrict__ fill,
                                                         Edge* __restrict__ edges,
                                                         const float* __restrict__ dinv, int E) {
    int cls = blockIdx.x & 7;
    int bic = blockIdx.x >> 3;            // block index within class
    int bpc = gridDim.x >> 3;             // blocks per class
    for (int e = bic * 256 + (int)threadIdx.x; e < E; e += bpc * 256) {
        int d = dst[e];
        if (((d >> 4) & 7) == cls) {
            int s = src[e];
            int p = atomicAdd(&fill[d], 1);
            Edge t;
            t.c = s;
            t.d = dinv[s];
            edges[rowptr[d] + p] = t;
        }
    }
}

// Gather-aggregate for one node (wave): a += sum_e d_e * h[c_e][lane].
// h rows are fp16 (128B/row): halves the gather line traffic vs fp32.
__device__ __forceinline__ float gather_agg(const __half* __restrict__ m,
                                            const Edge* __restrict__ ep, int n,
                                            float a, int lane) {
    int e = 0;
    for (; e + 16 <= n; e += 16) {
        Edge Ed[16];
        float v[16];
#pragma unroll
        for (int u = 0; u < 16; ++u) Ed[u] = ep[e + u];
#pragma unroll
        for (int u = 0; u < 16; ++u) v[u] = __half2float(m[(size_t)Ed[u].c * 64 + lane]);
#pragma unroll
        for (int u = 0; u < 16; ++u) a += Ed[u].d * v[u];
    }
    for (; e + 4 <= n; e += 4) {
        Edge Ed[4];
        float v[4];
#pragma unroll
        for (int u = 0; u < 4; ++u) Ed[u] = ep[e + u];
#pragma unroll
        for (int u = 0; u < 4; ++u) v[u] = __half2float(m[(size_t)Ed[u].c * 64 + lane]);
#pragma unroll
        for (int u = 0; u < 4; ++u) a += Ed[u].d * v[u];
    }
    for (; e < n; ++e) {
        Edge Ee = ep[e];
        a += Ee.d * __half2float(m[(size_t)Ee.c * 64 + lane]);
    }
    return a;
}

// ---------------- layer-0 aggregation: h1 = relu(di*a + b) ----------------
__global__ __launch_bounds__(256) void agg0_kernel(const __half* __restrict__ m,
                                                   const int* __restrict__ rowptr,
                                                   const Edge* __restrict__ edges,
                                                   const float* __restrict__ dinv,
                                                   const float* __restrict__ bias,
                                                   __half* __restrict__ hout, int N, int E) {
    int wid = __builtin_amdgcn_readfirstlane((blockIdx.x * 256 + threadIdx.x) >> 6);
    int lane = threadIdx.x & 63;
    if (wid >= N) return;
    int r0 = rowptr[wid];
    int r1 = (wid + 1 < N) ? rowptr[wid + 1] : E;
    float di = dinv[wid];
    float self = di * __half2float(m[(size_t)wid * 64 + lane]);
    float a = gather_agg(m, edges + r0, r1 - r0, self, lane);
    hout[(size_t)wid * 64 + lane] = __float2half(fmaxf(di * a + bias[lane], 0.0f));
}

// ---------------- fused layer, 2 nodes per wave: h' = relu((A h) W + b) ----------------
__global__ __launch_bounds__(256) void fused_kernel(const __half* __restrict__ h,
                                                    const int* __restrict__ rowptr,
                                                    const Edge* __restrict__ edges,
                                                    const float* __restrict__ dinv,
                                                    const float* __restrict__ W,
                                                    const float* __restrict__ bias,
                                                    __half* __restrict__ hout, int N, int E) {
    __shared__ float Ws[64 * 64];
    {
        const float4* W4 = (const float4*)W;
        float4* Ws4 = (float4*)Ws;
        for (int i = threadIdx.x; i < 64 * 16; i += 256) Ws4[i] = W4[i];
    }

    int wid = __builtin_amdgcn_readfirstlane((blockIdx.x * 256 + threadIdx.x) >> 6);
    int lane = threadIdx.x & 63;
    int nodeA = wid * 2;
    int nodeB = nodeA + 1;
    bool actA = (nodeA < N);
    bool actB = (nodeB < N);
    float gA = 0.0f, gB = 0.0f;

    if (actA) {
        int r0A = rowptr[nodeA];
        int r1A = rowptr[nodeB];   // nodeB==nodeA+1; valid since nodeA<N
        int r1B = 0, r0B = 0;
        float diA = dinv[nodeA], diB = 0.0f;
        float aA = diA * __half2float(h[(size_t)nodeA * 64 + lane]);
        float aB = 0.0f;
        if (actB) {
            r0B = r1A;
            r1B = (nodeB + 1 < N) ? rowptr[nodeB + 1] : E;
            diB = dinv[nodeB];
            aB = diB * __half2float(h[(size_t)nodeB * 64 + lane]);
        }
        const Edge* epA = edges + r0A;
        const Edge* epB = edges + r0B;
        int nA = r1A - r0A;
        int nB = r1B - r0B;
        int eA = 0, eB = 0;
        // combined rounds: 32 gathers in flight
        while (eA + 16 <= nA && eB + 16 <= nB) {
            Edge EdA[16], EdB[16];
            float vA[16], vB[16];
#pragma unroll
            for (int u = 0; u < 16; ++u) EdA[u] = epA[eA + u];
#pragma unroll
            for (int u = 0; u < 16; ++u) EdB[u] = epB[eB + u];
#pragma unroll
            for (int u = 0; u < 16; ++u) vA[u] = __half2float(h[(size_t)EdA[u].c * 64 + lane]);
#pragma unroll
            for (int u = 0; u < 16; ++u) vB[u] = __half2float(h[(size_t)EdB[u].c * 64 + lane]);
#pragma unroll
            for (int u = 0; u < 16; ++u) { aA += EdA[u].d * vA[u]; aB += EdB[u].d * vB[u]; }
            eA += 16;
            eB += 16;
        }
        aA = gather_agg(h, epA + eA, nA - eA, aA, lane);
        if (actB) aB = gather_agg(h, epB + eB, nB - eB, aB, lane);
        gA = diA * aA;
        gB = diB * aB;
    }

    __syncthreads();   // W staging visible; all waves arrive

    if (actA) {
        float bv = bias[lane];
        float accA = bv, accB = bv;
#pragma unroll
        for (int k = 0; k < 64; ++k) {
            float wv = Ws[k * 64 + lane];
            unsigned ga = __builtin_amdgcn_readlane(__float_as_uint(gA), k);
            unsigned gb = __builtin_amdgcn_readlane(__float_as_uint(gB), k);
            accA += __uint_as_float(ga) * wv;
            accB += __uint_as_float(gb) * wv;
        }
        hout[(size_t)nodeA * 64 + lane] = __float2half(fmaxf(accA, 0.0f));
        if (actB) hout[(size_t)nodeB * 64 + lane] = __float2half(fmaxf(accB, 0.0f));
    }
}

// ---------------- pooling: segment sum over sorted batch ids ----------------
__global__ __launch_bounds__(256) void pool_kernel(const __half* __restrict__ h,
                                                   const int* __restrict__ batch,
                                                   float* __restrict__ gpool, int N) {
    const int NPW = 32;  // nodes per wave
    int wid = (blockIdx.x * 256 + threadIdx.x) >> 6;
    int lane = threadIdx.x & 63;
    int i0 = wid * NPW;
    if (i0 >= N) return;
    int i1 = min(i0 + NPW, N);
    int curg = batch[i0];
    float acc = 0.0f;
    for (int i = i0; i < i1; ++i) {
        int g = batch[i];
        if (g != curg) {
            atomicAdd(&gpool[curg * 64 + lane], acc);
            acc = 0.0f;
            curg = g;
        }
        acc += __half2float(h[(size_t)i * 64 + lane]);
    }
    atomicAdd(&gpool[curg * 64 + lane], acc);
}

// ---------------- final: out = (gpool/count) @ Wlin + blin ----------------
__global__ void final_kernel(const float* __restrict__ gpool, const int* __restrict__ gcnt,
                             const float* __restrict__ Wlin, const float* __restrict__ blin,
                             float* __restrict__ out) {
    int t = threadIdx.x;
    if (t >= NGRAPH * COUT) return;
    int g = t / COUT, o = t - g * COUT;
    float c = (float)gcnt[g];
    if (c < 1.0f) c = 1.0f;
    float s = 0.0f;
    for (int k = 0; k < 64; ++k) s += gpool[g * 64 + k] * Wlin[k * COUT + o];
    out[t] = s / c + blin[o];
}

extern "C" void kernel_launch(void* const* d_in, const int* in_sizes, int n_in,
                              void* d_out, int out_size, void* d_ws, size_t ws_size,
                              hipStream_t stream) {
    const float* x    = (const float*)d_in[0];
    const int*   ei   = (const int*)d_in[1];
    const int*   batch= (const int*)d_in[2];
    const float* W0   = (const float*)d_in[3];
    const float* b0   = (const float*)d_in[4];
    const float* Ws   = (const float*)d_in[5];
    const float* bs   = (const float*)d_in[6];
    const float* Wlin = (const float*)d_in[7];
    const float* blin = (const float*)d_in[8];
    float* out = (float*)d_out;

    const int N = NNODES, E = NEDGES;
    const int* srcp = ei;          // edge_index[0]
    const int* dstp = ei + E;      // edge_index[1]

    char* w = (char*)d_ws;
    int*   cnt    = (int*)w;   w += (size_t)N * 4;
    int*   fill   = (int*)w;   w += (size_t)N * 4;
    float* gpool  = (float*)w; w += (size_t)NGRAPH * 64 * 4;
    size_t zero_bytes = (size_t)(w - (char*)d_ws);
    int*   gcnt   = (int*)w;   w += (size_t)NGRAPH * 4;
    int*   bsum   = (int*)w;   w += (size_t)512 * 4;
    float* dinv   = (float*)w; w += (size_t)N * 4;
    int*   rowptr = (int*)w;   w += (size_t)N * 4;
    Edge*  edges  = (Edge*)w;  w += (size_t)E * 8;
    __half* bufA  = (__half*)w; w += (size_t)N * 64 * 2;
    __half* bufB  = (__half*)w; w += (size_t)N * 64 * 2;

    hipMemsetAsync(d_ws, 0, zero_bytes, stream);

    int eblocks = (E + 255) / 256;   // 6250
    int nblocks = (N + 255) / 256;   // 391, fits scan_b's 512-thread block
    int gemmblocks = (N + 31) / 32;  // 3125: 8 rows/wave, 4 waves/block

    // count + layer-0 GEMM co-scheduled (independent)
    count_gemm_kernel<128><<<eblocks + gemmblocks, 256, 0, stream>>>(
        dstp, cnt, E, x, W0, bufB, N, eblocks);
    // dinv + gcnt co-scheduled
    dinv_gcnt_kernel<<<nblocks + 1, 256, 0, stream>>>(cnt, dinv, batch, gcnt, N, nblocks);
    scan_a<<<nblocks, 256, 0, stream>>>(cnt, rowptr, bsum, N);
    scan_b<<<1, 512, 0, stream>>>(bsum, nblocks);
    scan_c<<<nblocks, 256, 0, stream>>>(rowptr, bsum, N);
    fill_sweep_kernel<<<2048, 256, 0, stream>>>(srcp, dstp, rowptr, fill, edges, dinv, E);

    int aggblocks = (N + 3) / 4;              // wave per node (agg0)
    int fusedblocks = ((N + 1) / 2 + 3) / 4;  // 2 nodes per wave

    agg0_kernel<<<aggblocks, 256, 0, stream>>>(bufB, rowptr, edges, dinv, b0, bufA, N, E);

    // layers 1..9 fused: h' = relu((A h) W + b)
    __half* hin = bufA;
    __half* hout = bufB;
    for (int l = 0; l < NSTACK; ++l) {
        fused_kernel<<<fusedblocks, 256, 0, stream>>>(hin, rowptr, edges, dinv,
                                                      Ws + (size_t)l * 64 * 64,
                                                      bs + (size_t)l * 64, hout, N, E);
        __half* t = hin; hin = hout; hout = t;
    }
    // final h is in `hin` after the swap

    int pwaves = (N + 31) / 32;
    int pblocks = (pwaves + 3) / 4;
    pool_kernel<<<pblocks, 256, 0, stream>>>(hin, batch, gpool, N);
    final_kernel<<<1, 896, 0, stream>>>(gpool, gcnt, Wlin, blin, out);
}

// Round 8
// 891.500 us; speedup vs baseline: 2.9589x; 1.0003x over previous
//
#include <hip/hip_runtime.h>
#include <hip/hip_fp16.h>

#define NNODES 100000
#define NEDGES 1600000
#define NGRAPH 128
#define CIN 128
#define CH 64
#define COUT 7
#define NSTACK 9

struct alignas(8) Edge { int c; float d; };

// ---------------- merged: degree count (atomics, ILP-8) + layer-0 GEMM ----------------
template <int K>
__global__ __launch_bounds__(256) void count_gemm_kernel(const int* __restrict__ dst,
                                                         int* __restrict__ cnt, int E,
                                                         const float* __restrict__ h,
                                                         const float* __restrict__ W,
                                                         __half* __restrict__ m, int N,
                                                         int countBlocks) {
    __shared__ float Ws[K * 64];
    if (blockIdx.x < (unsigned)countBlocks) {
        // 8 edges per thread, strided for coalescing; 8 independent atomics in
        // flight per thread (latency-bound otherwise: 1 atomic/thread = 1 round).
        int base = blockIdx.x * 2048 + threadIdx.x;
#pragma unroll
        for (int u = 0; u < 8; ++u) {
            int e = base + u * 256;
            if (e < E) atomicAdd(&cnt[dst[e]], 1);
        }
        return;
    }
    // ---- GEMM part: 8 rows/wave ----
    int gb = blockIdx.x - countBlocks;
    for (int i = threadIdx.x; i < K * 64; i += 256) Ws[i] = W[i];
    __syncthreads();
    const int ROWS = 8;
    int wid = (gb * 256 + (int)threadIdx.x) >> 6;
    int lane = threadIdx.x & 63;
    long row0 = (long)wid * ROWS;
    if (row0 >= N) return;
    const float* hr = h + row0 * K + lane;

    float hv[ROWS][K / 64];
#pragma unroll
    for (int r = 0; r < ROWS; ++r)
#pragma unroll
        for (int q = 0; q < K / 64; ++q)
            hv[r][q] = hr[(size_t)r * K + q * 64];

    float acc[ROWS];
#pragma unroll
    for (int r = 0; r < ROWS; ++r) acc[r] = 0.0f;

#pragma unroll
    for (int k = 0; k < K; ++k) {
        float wv = Ws[k * 64 + lane];
#pragma unroll
        for (int r = 0; r < ROWS; ++r) {
            unsigned hb = __builtin_amdgcn_readlane(__float_as_uint(hv[r][k >> 6]), k & 63);
            acc[r] += __uint_as_float(hb) * wv;
        }
    }

    __half* mo = m + row0 * 64 + lane;
#pragma unroll
    for (int r = 0; r < ROWS; ++r) mo[r * 64] = __float2half(acc[r]);
}

// ---------------- merged: dinv + per-graph counts ----------------
__global__ void dinv_gcnt_kernel(const int* __restrict__ cnt, float* __restrict__ dinv,
                                 const int* __restrict__ batch, int* __restrict__ gcnt,
                                 int N, int nblocks) {
    if ((int)blockIdx.x == nblocks) {
        int g = threadIdx.x;
        if (g >= NGRAPH) return;
        auto lb = [&](int v) {
            int lo = 0, hi = N;
            while (lo < hi) {
                int mid = (lo + hi) >> 1;
                if (batch[mid] < v) lo = mid + 1; else hi = mid;
            }
            return lo;
        };
        gcnt[g] = lb(g + 1) - lb(g);
        return;
    }
    int i = blockIdx.x * 256 + threadIdx.x;
    if (i < N) dinv[i] = 1.0f / sqrtf((float)(cnt[i] + 1));  // +1 self-loop
}

// ---------------- exclusive scan (3-phase) ----------------
__global__ void scan_a(const int* __restrict__ cnt, int* __restrict__ rowptr,
                       int* __restrict__ bsum, int N) {
    __shared__ int s[256];
    int i = blockIdx.x * 256 + threadIdx.x;
    int v = (i < N) ? cnt[i] : 0;
    s[threadIdx.x] = v;
    __syncthreads();
    for (int d = 1; d < 256; d <<= 1) {
        int t = (threadIdx.x >= d) ? s[threadIdx.x - d] : 0;
        __syncthreads();
        s[threadIdx.x] += t;
        __syncthreads();
    }
    if (i < N) rowptr[i] = s[threadIdx.x] - v;   // exclusive
    if (threadIdx.x == 255) bsum[blockIdx.x] = s[255];
}

__global__ void scan_b(int* __restrict__ bsum, int nb) {
    __shared__ int s[512];
    int v = (threadIdx.x < nb) ? bsum[threadIdx.x] : 0;
    s[threadIdx.x] = v;
    __syncthreads();
    for (int d = 1; d < 512; d <<= 1) {
        int t = (threadIdx.x >= (unsigned)d) ? s[threadIdx.x - d] : 0;
        __syncthreads();
        s[threadIdx.x] += t;
        __syncthreads();
    }
    if (threadIdx.x < nb) bsum[threadIdx.x] = s[threadIdx.x] - v;  // exclusive
}

__global__ void scan_c(int* __restrict__ rowptr, const int* __restrict__ bsum, int N) {
    int i = blockIdx.x * 256 + threadIdx.x;
    if (i < N) rowptr[i] += bsum[blockIdx.x];
}

// ---------------- CSR fill, XCD-routed, ILP-4 atomic chains ----------------
__global__ __launch_bounds__(256) void fill_sweep_kernel(const int* __restrict__ src,
                                                         const int* __restrict__ dst,
                                                         const int* __restrict__ rowptr,
                                                         int* __restrict__ fill,
                                                         Edge* __restrict__ edges,
                                                         const float* __restrict__ dinv, int E) {
    int cls = blockIdx.x & 7;
    int bic = blockIdx.x >> 3;            // block index within class
    int bpc = gridDim.x >> 3;             // blocks per class
    int stride = bpc * 256;
    for (int e = bic * 256 + (int)threadIdx.x; e < E; e += stride * 4) {
        int ee[4], d[4], s[4], p[4];
        bool ok[4];
#pragma unroll
        for (int u = 0; u < 4; ++u) {
            ee[u] = e + u * stride;
            bool in = (ee[u] < E);
            d[u] = in ? dst[ee[u]] : 0;
            ok[u] = in && (((d[u] >> 4) & 7) == cls);
        }
#pragma unroll
        for (int u = 0; u < 4; ++u) if (ok[u]) s[u] = src[ee[u]];
        // 4 independent atomics in flight
#pragma unroll
        for (int u = 0; u < 4; ++u) if (ok[u]) p[u] = atomicAdd(&fill[d[u]], 1);
#pragma unroll
        for (int u = 0; u < 4; ++u) if (ok[u]) {
            Edge t;
            t.c = s[u];
            t.d = dinv[s[u]];
            edges[rowptr[d[u]] + p[u]] = t;
        }
    }
}

// Gather-aggregate for one node (wave): a += sum_e d_e * h[c_e][lane].
__device__ __forceinline__ float gather_agg(const __half* __restrict__ m,
                                            const Edge* __restrict__ ep, int n,
                                            float a, int lane) {
    int e = 0;
    for (; e + 16 <= n; e += 16) {
        Edge Ed[16];
        float v[16];
#pragma unroll
        for (int u = 0; u < 16; ++u) Ed[u] = ep[e + u];
#pragma unroll
        for (int u = 0; u < 16; ++u) v[u] = __half2float(m[(size_t)Ed[u].c * 64 + lane]);
#pragma unroll
        for (int u = 0; u < 16; ++u) a += Ed[u].d * v[u];
    }
    for (; e + 4 <= n; e += 4) {
        Edge Ed[4];
        float v[4];
#pragma unroll
        for (int u = 0; u < 4; ++u) Ed[u] = ep[e + u];
#pragma unroll
        for (int u = 0; u < 4; ++u) v[u] = __half2float(m[(size_t)Ed[u].c * 64 + lane]);
#pragma unroll
        for (int u = 0; u < 4; ++u) a += Ed[u].d * v[u];
    }
    for (; e < n; ++e) {
        Edge Ee = ep[e];
        a += Ee.d * __half2float(m[(size_t)Ee.c * 64 + lane]);
    }
    return a;
}

// ---------------- layer-0 aggregation: h1 = relu(di*a + b) ----------------
__global__ __launch_bounds__(256) void agg0_kernel(const __half* __restrict__ m,
                                                   const int* __restrict__ rowptr,
                                                   const Edge* __restrict__ edges,
                                                   const float* __restrict__ dinv,
                                                   const float* __restrict__ bias,
                                                   __half* __restrict__ hout, int N, int E) {
    int wid = __builtin_amdgcn_readfirstlane((blockIdx.x * 256 + threadIdx.x) >> 6);
    int lane = threadIdx.x & 63;
    if (wid >= N) return;
    int r0 = rowptr[wid];
    int r1 = (wid + 1 < N) ? rowptr[wid + 1] : E;
    float di = dinv[wid];
    float self = di * __half2float(m[(size_t)wid * 64 + lane]);
    float a = gather_agg(m, edges + r0, r1 - r0, self, lane);
    hout[(size_t)wid * 64 + lane] = __float2half(fmaxf(di * a + bias[lane], 0.0f));
}

// ---------------- fused layer, 2 nodes per wave: h' = relu((A h) W + b) ----------------
__global__ __launch_bounds__(256) void fused_kernel(const __half* __restrict__ h,
                                                    const int* __restrict__ rowptr,
                                                    const Edge* __restrict__ edges,
                                                    const float* __restrict__ dinv,
                                                    const float* __restrict__ W,
                                                    const float* __restrict__ bias,
                                                    __half* __restrict__ hout, int N, int E) {
    __shared__ float Ws[64 * 64];
    {
        const float4* W4 = (const float4*)W;
        float4* Ws4 = (float4*)Ws;
        for (int i = threadIdx.x; i < 64 * 16; i += 256) Ws4[i] = W4[i];
    }

    int wid = __builtin_amdgcn_readfirstlane((blockIdx.x * 256 + threadIdx.x) >> 6);
    int lane = threadIdx.x & 63;
    int nodeA = wid * 2;
    int nodeB = nodeA + 1;
    bool actA = (nodeA < N);
    bool actB = (nodeB < N);
    float gA = 0.0f, gB = 0.0f;

    if (actA) {
        int r0A = rowptr[nodeA];
        int r1A = rowptr[nodeB];   // nodeB==nodeA+1; valid since nodeA<N
        int r1B = 0, r0B = 0;
        float diA = dinv[nodeA], diB = 0.0f;
        float aA = diA * __half2float(h[(size_t)nodeA * 64 + lane]);
        float aB = 0.0f;
        if (actB) {
            r0B = r1A;
            r1B = (nodeB + 1 < N) ? rowptr[nodeB + 1] : E;
            diB = dinv[nodeB];
            aB = diB * __half2float(h[(size_t)nodeB * 64 + lane]);
        }
        const Edge* epA = edges + r0A;
        const Edge* epB = edges + r0B;
        int nA = r1A - r0A;
        int nB = r1B - r0B;
        int eA = 0, eB = 0;
        // combined rounds: 32 gathers in flight
        while (eA + 16 <= nA && eB + 16 <= nB) {
            Edge EdA[16], EdB[16];
            float vA[16], vB[16];
#pragma unroll
            for (int u = 0; u < 16; ++u) EdA[u] = epA[eA + u];
#pragma unroll
            for (int u = 0; u < 16; ++u) EdB[u] = epB[eB + u];
#pragma unroll
            for (int u = 0; u < 16; ++u) vA[u] = __half2float(h[(size_t)EdA[u].c * 64 + lane]);
#pragma unroll
            for (int u = 0; u < 16; ++u) vB[u] = __half2float(h[(size_t)EdB[u].c * 64 + lane]);
#pragma unroll
            for (int u = 0; u < 16; ++u) { aA += EdA[u].d * vA[u]; aB += EdB[u].d * vB[u]; }
            eA += 16;
            eB += 16;
        }
        aA = gather_agg(h, epA + eA, nA - eA, aA, lane);
        if (actB) aB = gather_agg(h, epB + eB, nB - eB, aB, lane);
        gA = diA * aA;
        gB = diB * aB;
    }

    __syncthreads();   // W staging visible; all waves arrive

    if (actA) {
        float bv = bias[lane];
        float accA = bv, accB = bv;
#pragma unroll
        for (int k = 0; k < 64; ++k) {
            float wv = Ws[k * 64 + lane];
            unsigned ga = __builtin_amdgcn_readlane(__float_as_uint(gA), k);
            unsigned gb = __builtin_amdgcn_readlane(__float_as_uint(gB), k);
            accA += __uint_as_float(ga) * wv;
            accB += __uint_as_float(gb) * wv;
        }
        hout[(size_t)nodeA * 64 + lane] = __float2half(fmaxf(accA, 0.0f));
        if (actB) hout[(size_t)nodeB * 64 + lane] = __float2half(fmaxf(accB, 0.0f));
    }
}

// ---------------- pooling: segment sum over sorted batch ids ----------------
__global__ __launch_bounds__(256) void pool_kernel(const __half* __restrict__ h,
                                                   const int* __restrict__ batch,
                                                   float* __restrict__ gpool, int N) {
    const int NPW = 32;  // nodes per wave
    int wid = (blockIdx.x * 256 + threadIdx.x) >> 6;
    int lane = threadIdx.x & 63;
    int i0 = wid * NPW;
    if (i0 >= N) return;
    int i1 = min(i0 + NPW, N);
    int curg = batch[i0];
    float acc = 0.0f;
    for (int i = i0; i < i1; ++i) {
        int g = batch[i];
        if (g != curg) {
            atomicAdd(&gpool[curg * 64 + lane], acc);
            acc = 0.0f;
            curg = g;
        }
        acc += __half2float(h[(size_t)i * 64 + lane]);
    }
    atomicAdd(&gpool[curg * 64 + lane], acc);
}

// ---------------- final: out = (gpool/count) @ Wlin + blin ----------------
__global__ void final_kernel(const float* __restrict__ gpool, const int* __restrict__ gcnt,
                             const float* __restrict__ Wlin, const float* __restrict__ blin,
                             float* __restrict__ out) {
    int t = threadIdx.x;
    if (t >= NGRAPH * COUT) return;
    int g = t / COUT, o = t - g * COUT;
    float c = (float)gcnt[g];
    if (c < 1.0f) c = 1.0f;
    float s = 0.0f;
    for (int k = 0; k < 64; ++k) s += gpool[g * 64 + k] * Wlin[k * COUT + o];
    out[t] = s / c + blin[o];
}

extern "C" void kernel_launch(void* const* d_in, const int* in_sizes, int n_in,
                              void* d_out, int out_size, void* d_ws, size_t ws_size,
                              hipStream_t stream) {
    const float* x    = (const float*)d_in[0];
    const int*   ei   = (const int*)d_in[1];
    const int*   batch= (const int*)d_in[2];
    const float* W0   = (const float*)d_in[3];
    const float* b0   = (const float*)d_in[4];
    const float* Ws   = (const float*)d_in[5];
    const float* bs   = (const float*)d_in[6];
    const float* Wlin = (const float*)d_in[7];
    const float* blin = (const float*)d_in[8];
    float* out = (float*)d_out;

    const int N = NNODES, E = NEDGES;
    const int* srcp = ei;          // edge_index[0]
    const int* dstp = ei + E;      // edge_index[1]

    char* w = (char*)d_ws;
    int*   cnt    = (int*)w;   w += (size_t)N * 4;
    int*   fill   = (int*)w;   w += (size_t)N * 4;
    float* gpool  = (float*)w; w += (size_t)NGRAPH * 64 * 4;
    size_t zero_bytes = (size_t)(w - (char*)d_ws);
    int*   gcnt   = (int*)w;   w += (size_t)NGRAPH * 4;
    int*   bsum   = (int*)w;   w += (size_t)512 * 4;
    float* dinv   = (float*)w; w += (size_t)N * 4;
    int*   rowptr = (int*)w;   w += (size_t)N * 4;
    Edge*  edges  = (Edge*)w;  w += (size_t)E * 8;
    __half* bufA  = (__half*)w; w += (size_t)N * 64 * 2;
    __half* bufB  = (__half*)w; w += (size_t)N * 64 * 2;

    hipMemsetAsync(d_ws, 0, zero_bytes, stream);

    int countBlocks = (E + 2047) / 2048;  // 782: 8 edges/thread, ILP-8 atomics
    int nblocks = (N + 255) / 256;        // 391, fits scan_b's 512-thread block
    int gemmblocks = (N + 31) / 32;       // 3125: 8 rows/wave, 4 waves/block

    // count + layer-0 GEMM co-scheduled (independent)
    count_gemm_kernel<128><<<countBlocks + gemmblocks, 256, 0, stream>>>(
        dstp, cnt, E, x, W0, bufB, N, countBlocks);
    // dinv + gcnt co-scheduled
    dinv_gcnt_kernel<<<nblocks + 1, 256, 0, stream>>>(cnt, dinv, batch, gcnt, N, nblocks);
    scan_a<<<nblocks, 256, 0, stream>>>(cnt, rowptr, bsum, N);
    scan_b<<<1, 512, 0, stream>>>(bsum, nblocks);
    scan_c<<<nblocks, 256, 0, stream>>>(rowptr, bsum, N);
    fill_sweep_kernel<<<2048, 256, 0, stream>>>(srcp, dstp, rowptr, fill, edges, dinv, E);

    int aggblocks = (N + 3) / 4;              // wave per node (agg0)
    int fusedblocks = ((N + 1) / 2 + 3) / 4;  // 2 nodes per wave

    agg0_kernel<<<aggblocks, 256, 0, stream>>>(bufB, rowptr, edges, dinv, b0, bufA, N, E);

    // layers 1..9 fused: h' = relu((A h) W + b)
    __half* hin = bufA;
    __half* hout = bufB;
    for (int l = 0; l < NSTACK; ++l) {
        fused_kernel<<<fusedblocks, 256, 0, stream>>>(hin, rowptr, edges, dinv,
                                                      Ws + (size_t)l * 64 * 64,
                                                      bs + (size_t)l * 64, hout, N, E);
        __half* t = hin; hin = hout; hout = t;
    }
    // final h is in `hin` after the swap

    int pwaves = (N + 31) / 32;
    int pblocks = (pwaves + 3) / 4;
    pool_kernel<<<pblocks, 256, 0, stream>>>(hin, batch, gpool, N);
    final_kernel<<<1, 896, 0, stream>>>(gpool, gcnt, Wlin, blin, out);
}

// Round 9
// 873.183 us; speedup vs baseline: 3.0210x; 1.0210x over previous
//
#include <hip/hip_runtime.h>
#include <hip/hip_fp16.h>

#define NNODES 100000
#define NEDGES 1600000
#define NGRAPH 128
#define CIN 128
#define CH 64
#define COUT 7
#define NSTACK 9

#define NB 391      // buckets of 256 nodes: ceil(100000/256)
#define CHUNK 2048  // edges per histogram/scatter block
#define NC 782      // ceil(1600000/2048)

struct alignas(8) Edge { int c; float d; };

// ---------------- merged: P1 bucket histogram (LDS only) + layer-0 GEMM ----------------
template <int K>
__global__ __launch_bounds__(256) void hist_gemm_kernel(const int* __restrict__ dst,
                                                        int* __restrict__ hist, int E,
                                                        const float* __restrict__ h,
                                                        const float* __restrict__ W,
                                                        __half* __restrict__ m, int N,
                                                        int histBlocks) {
    __shared__ float Ws[K * 64];
    __shared__ int lh[NB];
    if (blockIdx.x < (unsigned)histBlocks) {
        for (int i = threadIdx.x; i < NB; i += 256) lh[i] = 0;
        __syncthreads();
        int e0 = blockIdx.x * CHUNK;
        int e1 = min(e0 + CHUNK, E);
        for (int e = e0 + threadIdx.x; e < e1; e += 256)
            atomicAdd(&lh[dst[e] >> 8], 1);   // LDS atomic
        __syncthreads();
        for (int i = threadIdx.x; i < NB; i += 256) hist[i * NC + (int)blockIdx.x] = lh[i];
        return;
    }
    // ---- GEMM part: 8 rows/wave ----
    int gb = blockIdx.x - histBlocks;
    for (int i = threadIdx.x; i < K * 64; i += 256) Ws[i] = W[i];
    __syncthreads();
    const int ROWS = 8;
    int wid = (gb * 256 + (int)threadIdx.x) >> 6;
    int lane = threadIdx.x & 63;
    long row0 = (long)wid * ROWS;
    if (row0 >= N) return;
    const float* hr = h + row0 * K + lane;

    float hv[ROWS][K / 64];
#pragma unroll
    for (int r = 0; r < ROWS; ++r)
#pragma unroll
        for (int q = 0; q < K / 64; ++q)
            hv[r][q] = hr[(size_t)r * K + q * 64];

    float acc[ROWS];
#pragma unroll
    for (int r = 0; r < ROWS; ++r) acc[r] = 0.0f;

#pragma unroll
    for (int k = 0; k < K; ++k) {
        float wv = Ws[k * 64 + lane];
#pragma unroll
        for (int r = 0; r < ROWS; ++r) {
            unsigned hb = __builtin_amdgcn_readlane(__float_as_uint(hv[r][k >> 6]), k & 63);
            acc[r] += __uint_as_float(hb) * wv;
        }
    }

    __half* mo = m + row0 * 64 + lane;
#pragma unroll
    for (int r = 0; r < ROWS; ++r) mo[r * 64] = __float2half(acc[r]);
}

// ---------------- P2a: exclusive scan of each bucket row over NC chunks ----------------
__global__ __launch_bounds__(256) void scan_chunks_kernel(int* __restrict__ hist,
                                                          int* __restrict__ btot) {
    int b = blockIdx.x;
    int t = threadIdx.x;
    int* row = hist + b * NC;
    int v[4];
    int base = 4 * t;   // 4 elements/thread covers 1024 >= NC
#pragma unroll
    for (int u = 0; u < 4; ++u) v[u] = (base + u < NC) ? row[base + u] : 0;
    int tsum = v[0] + v[1] + v[2] + v[3];
    __shared__ int s[256];
    s[t] = tsum;
    __syncthreads();
    for (int d = 1; d < 256; d <<= 1) {
        int x = (t >= d) ? s[t - d] : 0;
        __syncthreads();
        s[t] += x;
        __syncthreads();
    }
    int run = s[t] - tsum;   // exclusive prefix of thread sums
    if (t == 255) btot[b] = s[255];
#pragma unroll
    for (int u = 0; u < 4; ++u) {
        if (base + u < NC) row[base + u] = run;
        run += v[u];
    }
}

// ---------------- P2b: exclusive scan of bucket totals -> bucket bases ----------------
__global__ void scan_buckets_kernel(const int* __restrict__ btot, int* __restrict__ bbase) {
    __shared__ int s[512];
    int t = threadIdx.x;
    int v = (t < NB) ? btot[t] : 0;
    s[t] = v;
    __syncthreads();
    for (int d = 1; d < 512; d <<= 1) {
        int x = (t >= d) ? s[t - d] : 0;
        __syncthreads();
        s[t] += x;
        __syncthreads();
    }
    if (t < NB) bbase[t] = s[t] - v;
}

// ---------------- P3: scatter edges into dst buckets (LDS ranks, no global atomics) ----
__global__ __launch_bounds__(256) void scatter_kernel(const int* __restrict__ src,
                                                      const int* __restrict__ dst,
                                                      const int* __restrict__ hist,
                                                      const int* __restrict__ bbase,
                                                      int* __restrict__ src_b,
                                                      int* __restrict__ dst_b, int E) {
    __shared__ int offs[NB];
    for (int b = threadIdx.x; b < NB; b += 256)
        offs[b] = hist[b * NC + (int)blockIdx.x] + bbase[b];
    __syncthreads();
    int e0 = blockIdx.x * CHUNK;
    int e1 = min(e0 + CHUNK, E);
    for (int e = e0 + threadIdx.x; e < e1; e += 256) {
        int d = dst[e], s = src[e];
        int pos = atomicAdd(&offs[d >> 8], 1);   // LDS atomic
        src_b[pos] = s;
        dst_b[pos] = d;
    }
}

// ---------------- B1: per-bucket node degree count (LDS, no global atomics) ------------
__global__ __launch_bounds__(256) void bucket_count_kernel(const int* __restrict__ dst_b,
                                                           const int* __restrict__ bbase,
                                                           const int* __restrict__ btot,
                                                           int* __restrict__ cnt, int N) {
    __shared__ int c256[256];
    int t = threadIdx.x;
    c256[t] = 0;
    __syncthreads();
    int lo = bbase[blockIdx.x], n = btot[blockIdx.x];
    for (int e = lo + t; e < lo + n; e += 256) atomicAdd(&c256[dst_b[e] & 255], 1);
    __syncthreads();
    int node = blockIdx.x * 256 + t;
    if (node < N) cnt[node] = c256[t];
}

// ---------------- merged: dinv + per-graph counts ----------------
__global__ void dinv_gcnt_kernel(const int* __restrict__ cnt, float* __restrict__ dinv,
                                 const int* __restrict__ batch, int* __restrict__ gcnt,
                                 int N, int nblocks) {
    if ((int)blockIdx.x == nblocks) {
        int g = threadIdx.x;
        if (g >= NGRAPH) return;
        auto lb = [&](int v) {
            int lo = 0, hi = N;
            while (lo < hi) {
                int mid = (lo + hi) >> 1;
                if (batch[mid] < v) lo = mid + 1; else hi = mid;
            }
            return lo;
        };
        gcnt[g] = lb(g + 1) - lb(g);
        return;
    }
    int i = blockIdx.x * 256 + threadIdx.x;
    if (i < N) dinv[i] = 1.0f / sqrtf((float)(cnt[i] + 1));  // +1 self-loop
}

// ---------------- exclusive scan (3-phase) for rowptr ----------------
__global__ void scan_a(const int* __restrict__ cnt, int* __restrict__ rowptr,
                       int* __restrict__ bsum, int N) {
    __shared__ int s[256];
    int i = blockIdx.x * 256 + threadIdx.x;
    int v = (i < N) ? cnt[i] : 0;
    s[threadIdx.x] = v;
    __syncthreads();
    for (int d = 1; d < 256; d <<= 1) {
        int t = (threadIdx.x >= d) ? s[threadIdx.x - d] : 0;
        __syncthreads();
        s[threadIdx.x] += t;
        __syncthreads();
    }
    if (i < N) rowptr[i] = s[threadIdx.x] - v;   // exclusive
    if (threadIdx.x == 255) bsum[blockIdx.x] = s[255];
}

__global__ void scan_b(int* __restrict__ bsum, int nb) {
    __shared__ int s[512];
    int v = (threadIdx.x < nb) ? bsum[threadIdx.x] : 0;
    s[threadIdx.x] = v;
    __syncthreads();
    for (int d = 1; d < 512; d <<= 1) {
        int t = (threadIdx.x >= (unsigned)d) ? s[threadIdx.x - d] : 0;
        __syncthreads();
        s[threadIdx.x] += t;
        __syncthreads();
    }
    if (threadIdx.x < nb) bsum[threadIdx.x] = s[threadIdx.x] - v;  // exclusive
}

__global__ void scan_c(int* __restrict__ rowptr, const int* __restrict__ bsum, int N) {
    int i = blockIdx.x * 256 + threadIdx.x;
    if (i < N) rowptr[i] += bsum[blockIdx.x];
}

// ---------------- B2: per-bucket CSR fill (LDS ranks; contiguous block-local writes) ----
__global__ __launch_bounds__(256) void bucket_fill_kernel(const int* __restrict__ src_b,
                                                          const int* __restrict__ dst_b,
                                                          const int* __restrict__ bbase,
                                                          const int* __restrict__ btot,
                                                          const int* __restrict__ rowptr,
                                                          const float* __restrict__ dinv,
                                                          Edge* __restrict__ edges, int N) {
    __shared__ int f256[256];
    __shared__ int rp[256];
    int t = threadIdx.x;
    f256[t] = 0;
    int node = blockIdx.x * 256 + t;
    rp[t] = (node < N) ? rowptr[node] : 0;
    __syncthreads();
    int lo = bbase[blockIdx.x], n = btot[blockIdx.x];
    for (int e = lo + t; e < lo + n; e += 256) {
        int d = dst_b[e], s = src_b[e];
        int li = d & 255;
        int slot = atomicAdd(&f256[li], 1);   // LDS atomic
        Edge te;
        te.c = s;
        te.d = dinv[s];   // dinv is 400KB -> L2-resident
        edges[rp[li] + slot] = te;
    }
}

// Gather-aggregate for one node (wave): a += sum_e d_e * h[c_e][lane].
__device__ __forceinline__ float gather_agg(const __half* __restrict__ m,
                                            const Edge* __restrict__ ep, int n,
                                            float a, int lane) {
    int e = 0;
    for (; e + 16 <= n; e += 16) {
        Edge Ed[16];
        float v[16];
#pragma unroll
        for (int u = 0; u < 16; ++u) Ed[u] = ep[e + u];
#pragma unroll
        for (int u = 0; u < 16; ++u) v[u] = __half2float(m[(size_t)Ed[u].c * 64 + lane]);
#pragma unroll
        for (int u = 0; u < 16; ++u) a += Ed[u].d * v[u];
    }
    for (; e + 4 <= n; e += 4) {
        Edge Ed[4];
        float v[4];
#pragma unroll
        for (int u = 0; u < 4; ++u) Ed[u] = ep[e + u];
#pragma unroll
        for (int u = 0; u < 4; ++u) v[u] = __half2float(m[(size_t)Ed[u].c * 64 + lane]);
#pragma unroll
        for (int u = 0; u < 4; ++u) a += Ed[u].d * v[u];
    }
    for (; e < n; ++e) {
        Edge Ee = ep[e];
        a += Ee.d * __half2float(m[(size_t)Ee.c * 64 + lane]);
    }
    return a;
}

// ---------------- layer-0 aggregation: h1 = relu(di*a + b) ----------------
__global__ __launch_bounds__(256) void agg0_kernel(const __half* __restrict__ m,
                                                   const int* __restrict__ rowptr,
                                                   const Edge* __restrict__ edges,
                                                   const float* __restrict__ dinv,
                                                   const float* __restrict__ bias,
                                                   __half* __restrict__ hout, int N, int E) {
    int wid = __builtin_amdgcn_readfirstlane((blockIdx.x * 256 + threadIdx.x) >> 6);
    int lane = threadIdx.x & 63;
    if (wid >= N) return;
    int r0 = rowptr[wid];
    int r1 = (wid + 1 < N) ? rowptr[wid + 1] : E;
    float di = dinv[wid];
    float self = di * __half2float(m[(size_t)wid * 64 + lane]);
    float a = gather_agg(m, edges + r0, r1 - r0, self, lane);
    hout[(size_t)wid * 64 + lane] = __float2half(fmaxf(di * a + bias[lane], 0.0f));
}

// ---------------- fused layer, 2 nodes per wave: h' = relu((A h) W + b) ----------------
__global__ __launch_bounds__(256) void fused_kernel(const __half* __restrict__ h,
                                                    const int* __restrict__ rowptr,
                                                    const Edge* __restrict__ edges,
                                                    const float* __restrict__ dinv,
                                                    const float* __restrict__ W,
                                                    const float* __restrict__ bias,
                                                    __half* __restrict__ hout, int N, int E) {
    __shared__ float Ws[64 * 64];
    {
        const float4* W4 = (const float4*)W;
        float4* Ws4 = (float4*)Ws;
        for (int i = threadIdx.x; i < 64 * 16; i += 256) Ws4[i] = W4[i];
    }

    int wid = __builtin_amdgcn_readfirstlane((blockIdx.x * 256 + threadIdx.x) >> 6);
    int lane = threadIdx.x & 63;
    int nodeA = wid * 2;
    int nodeB = nodeA + 1;
    bool actA = (nodeA < N);
    bool actB = (nodeB < N);
    float gA = 0.0f, gB = 0.0f;

    if (actA) {
        int r0A = rowptr[nodeA];
        int r1A = rowptr[nodeB];   // nodeB==nodeA+1; valid since nodeA<N
        int r1B = 0, r0B = 0;
        float diA = dinv[nodeA], diB = 0.0f;
        float aA = diA * __half2float(h[(size_t)nodeA * 64 + lane]);
        float aB = 0.0f;
        if (actB) {
            r0B = r1A;
            r1B = (nodeB + 1 < N) ? rowptr[nodeB + 1] : E;
            diB = dinv[nodeB];
            aB = diB * __half2float(h[(size_t)nodeB * 64 + lane]);
        }
        const Edge* epA = edges + r0A;
        const Edge* epB = edges + r0B;
        int nA = r1A - r0A;
        int nB = r1B - r0B;
        int eA = 0, eB = 0;
        // combined rounds: 32 gathers in flight
        while (eA + 16 <= nA && eB + 16 <= nB) {
            Edge EdA[16], EdB[16];
            float vA[16], vB[16];
#pragma unroll
            for (int u = 0; u < 16; ++u) EdA[u] = epA[eA + u];
#pragma unroll
            for (int u = 0; u < 16; ++u) EdB[u] = epB[eB + u];
#pragma unroll
            for (int u = 0; u < 16; ++u) vA[u] = __half2float(h[(size_t)EdA[u].c * 64 + lane]);
#pragma unroll
            for (int u = 0; u < 16; ++u) vB[u] = __half2float(h[(size_t)EdB[u].c * 64 + lane]);
#pragma unroll
            for (int u = 0; u < 16; ++u) { aA += EdA[u].d * vA[u]; aB += EdB[u].d * vB[u]; }
            eA += 16;
            eB += 16;
        }
        aA = gather_agg(h, epA + eA, nA - eA, aA, lane);
        if (actB) aB = gather_agg(h, epB + eB, nB - eB, aB, lane);
        gA = diA * aA;
        gB = diB * aB;
    }

    __syncthreads();   // W staging visible; all waves arrive

    if (actA) {
        float bv = bias[lane];
        float accA = bv, accB = bv;
#pragma unroll
        for (int k = 0; k < 64; ++k) {
            float wv = Ws[k * 64 + lane];
            unsigned ga = __builtin_amdgcn_readlane(__float_as_uint(gA), k);
            unsigned gb = __builtin_amdgcn_readlane(__float_as_uint(gB), k);
            accA += __uint_as_float(ga) * wv;
            accB += __uint_as_float(gb) * wv;
        }
        hout[(size_t)nodeA * 64 + lane] = __float2half(fmaxf(accA, 0.0f));
        if (actB) hout[(size_t)nodeB * 64 + lane] = __float2half(fmaxf(accB, 0.0f));
    }
}

// ---------------- pooling: segment sum over sorted batch ids ----------------
__global__ __launch_bounds__(256) void pool_kernel(const __half* __restrict__ h,
                                                   const int* __restrict__ batch,
                                                   float* __restrict__ gpool, int N) {
    const int NPW = 32;  // nodes per wave
    int wid = (blockIdx.x * 256 + threadIdx.x) >> 6;
    int lane = threadIdx.x & 63;
    int i0 = wid * NPW;
    if (i0 >= N) return;
    int i1 = min(i0 + NPW, N);
    int curg = batch[i0];
    float acc = 0.0f;
    for (int i = i0; i < i1; ++i) {
        int g = batch[i];
        if (g != curg) {
            atomicAdd(&gpool[curg * 64 + lane], acc);
            acc = 0.0f;
            curg = g;
        }
        acc += __half2float(h[(size_t)i * 64 + lane]);
    }
    atomicAdd(&gpool[curg * 64 + lane], acc);
}

// ---------------- final: out = (gpool/count) @ Wlin + blin ----------------
__global__ void final_kernel(const float* __restrict__ gpool, const int* __restrict__ gcnt,
                             const float* __restrict__ Wlin, const float* __restrict__ blin,
                             float* __restrict__ out) {
    int t = threadIdx.x;
    if (t >= NGRAPH * COUT) return;
    int g = t / COUT, o = t - g * COUT;
    float c = (float)gcnt[g];
    if (c < 1.0f) c = 1.0f;
    float s = 0.0f;
    for (int k = 0; k < 64; ++k) s += gpool[g * 64 + k] * Wlin[k * COUT + o];
    out[t] = s / c + blin[o];
}

extern "C" void kernel_launch(void* const* d_in, const int* in_sizes, int n_in,
                              void* d_out, int out_size, void* d_ws, size_t ws_size,
                              hipStream_t stream) {
    const float* x    = (const float*)d_in[0];
    const int*   ei   = (const int*)d_in[1];
    const int*   batch= (const int*)d_in[2];
    const float* W0   = (const float*)d_in[3];
    const float* b0   = (const float*)d_in[4];
    const float* Ws   = (const float*)d_in[5];
    const float* bs   = (const float*)d_in[6];
    const float* Wlin = (const float*)d_in[7];
    const float* blin = (const float*)d_in[8];
    float* out = (float*)d_out;

    const int N = NNODES, E = NEDGES;
    const int* srcp = ei;          // edge_index[0]
    const int* dstp = ei + E;      // edge_index[1]

    char* w = (char*)d_ws;
    float* gpool  = (float*)w; w += (size_t)NGRAPH * 64 * 4;
    size_t zero_bytes = (size_t)(w - (char*)d_ws);   // only gpool needs zeroing
    int*   cnt    = (int*)w;   w += (size_t)N * 4;
    int*   gcnt   = (int*)w;   w += (size_t)NGRAPH * 4;
    int*   bsum   = (int*)w;   w += (size_t)512 * 4;
    float* dinv   = (float*)w; w += (size_t)N * 4;
    int*   rowptr = (int*)w;   w += (size_t)N * 4;
    int*   hist   = (int*)w;   w += (size_t)NB * NC * 4;
    int*   btot   = (int*)w;   w += (size_t)NB * 4;
    int*   bbase  = (int*)w;   w += (size_t)NB * 4;
    int*   src_b  = (int*)w;   w += (size_t)E * 4;
    int*   dst_b  = (int*)w;   w += (size_t)E * 4;
    Edge*  edges  = (Edge*)w;  w += (size_t)E * 8;
    __half* bufA  = (__half*)w; w += (size_t)N * 64 * 2;
    __half* bufB  = (__half*)w; w += (size_t)N * 64 * 2;

    hipMemsetAsync(d_ws, 0, zero_bytes, stream);

    int nblocks = (N + 255) / 256;        // 391, fits scan_b's 512-thread block
    int gemmblocks = (N + 31) / 32;       // 3125: 8 rows/wave, 4 waves/block

    // P1 histogram + layer-0 GEMM co-scheduled (independent)
    hist_gemm_kernel<128><<<NC + gemmblocks, 256, 0, stream>>>(
        dstp, hist, E, x, W0, bufB, N, NC);
    scan_chunks_kernel<<<NB, 256, 0, stream>>>(hist, btot);
    scan_buckets_kernel<<<1, 512, 0, stream>>>(btot, bbase);
    scatter_kernel<<<NC, 256, 0, stream>>>(srcp, dstp, hist, bbase, src_b, dst_b, E);
    bucket_count_kernel<<<NB, 256, 0, stream>>>(dst_b, bbase, btot, cnt, N);
    dinv_gcnt_kernel<<<nblocks + 1, 256, 0, stream>>>(cnt, dinv, batch, gcnt, N, nblocks);
    scan_a<<<nblocks, 256, 0, stream>>>(cnt, rowptr, bsum, N);
    scan_b<<<1, 512, 0, stream>>>(bsum, nblocks);
    scan_c<<<nblocks, 256, 0, stream>>>(rowptr, bsum, N);
    bucket_fill_kernel<<<NB, 256, 0, stream>>>(src_b, dst_b, bbase, btot, rowptr, dinv,
                                               edges, N);

    int aggblocks = (N + 3) / 4;              // wave per node (agg0)
    int fusedblocks = ((N + 1) / 2 + 3) / 4;  // 2 nodes per wave

    agg0_kernel<<<aggblocks, 256, 0, stream>>>(bufB, rowptr, edges, dinv, b0, bufA, N, E);

    // layers 1..9 fused: h' = relu((A h) W + b)
    __half* hin = bufA;
    __half* hout = bufB;
    for (int l = 0; l < NSTACK; ++l) {
        fused_kernel<<<fusedblocks, 256, 0, stream>>>(hin, rowptr, edges, dinv,
                                                      Ws + (size_t)l * 64 * 64,
                                                      bs + (size_t)l * 64, hout, N, E);
        __half* t = hin; hin = hout; hout = t;
    }
    // final h is in `hin` after the swap

    int pwaves = (N + 31) / 32;
    int pblocks = (pwaves + 3) / 4;
    pool_kernel<<<pblocks, 256, 0, stream>>>(hin, batch, gpool, N);
    final_kernel<<<1, 896, 0, stream>>>(gpool, gcnt, Wlin, blin, out);
}